// Round 1
// baseline (1621.006 us; speedup 1.0000x reference)
//
#include <hip/hip_runtime.h>
#include <math.h>

// ToxicityGATv2 — full-pipeline fp32 implementation (round 0: correctness first).
// Softmax max-shift elided (|alpha| small; softmax is shift-invariant) -> single
// fused edge pass per layer with atomic denom/agg accumulation.

constexpr int N_ = 50000;
constexpr int E_ = 400000;
constexpr int G_ = 2000;
constexpr int H_ = 128;
constexpr int HEADS_ = 4;
constexpr int HD_ = 32;
constexpr int IN_ = 39;

// ---------------- utility ----------------
__device__ __forceinline__ void atomicMaxF(float* addr, float val) {
  int* ai = (int*)addr;
  int old = __float_as_int(*addr);
  while (__int_as_float(old) < val) {
    int prev = atomicCAS(ai, old, __float_as_int(val));
    if (prev == old) break;
    old = prev;
  }
}

// ---------------- input GEMM: y = x @ in_W + in_b  [N,39]x[39,128] ----------------
__global__ __launch_bounds__(128) void in_gemm(const float* __restrict__ x,
                                               const float* __restrict__ W,
                                               const float* __restrict__ b,
                                               float* __restrict__ y) {
  __shared__ float xs[16][40];  // 16 rows, K=39 (pad)
  int t = threadIdx.x;
  int row0 = blockIdx.x * 16;
  for (int i = t; i < 16 * IN_; i += 128) {
    int r = i / IN_, k = i % IN_;
    int row = row0 + r;
    xs[r][k] = (row < N_) ? x[row * IN_ + k] : 0.f;
  }
  __syncthreads();
  float acc[16];
#pragma unroll
  for (int r = 0; r < 16; r++) acc[r] = 0.f;
  for (int k = 0; k < IN_; k++) {
    float w = W[k * H_ + t];
#pragma unroll
    for (int r = 0; r < 16; r++) acc[r] = fmaf(xs[r][k], w, acc[r]);
  }
  float bb = b[t];
#pragma unroll
  for (int r = 0; r < 16; r++) {
    int row = row0 + r;
    if (row < N_) y[row * H_ + t] = acc[r] + bb;
  }
}

// ---------------- per-layer node GEMM: xl = xn@Wl, xr = xn@Wr ----------------
__global__ __launch_bounds__(256) void gemm_xlxr(const float* __restrict__ xn,
                                                 const float* __restrict__ Wlp,
                                                 const float* __restrict__ Wrp,
                                                 float* __restrict__ xl,
                                                 float* __restrict__ xr) {
  __shared__ float xs[32][H_];  // 16 KB
  int t = threadIdx.x;
  int row0 = blockIdx.x * 32;
  for (int i = t; i < 32 * H_; i += 256) {
    int r = i >> 7, c = i & 127;
    int row = row0 + r;
    xs[r][c] = (row < N_) ? xn[row * H_ + c] : 0.f;
  }
  __syncthreads();
  int c = t & 127;
  const float* W = (t < 128) ? Wlp : Wrp;
  float* out = (t < 128) ? xl : xr;
  float acc[32];
#pragma unroll
  for (int r = 0; r < 32; r++) acc[r] = 0.f;
  for (int k = 0; k < H_; k += 4) {
    float w0 = W[(k + 0) * H_ + c];
    float w1 = W[(k + 1) * H_ + c];
    float w2 = W[(k + 2) * H_ + c];
    float w3 = W[(k + 3) * H_ + c];
#pragma unroll
    for (int r = 0; r < 32; r++) {
      float4 xv = *(const float4*)&xs[r][k];
      acc[r] = fmaf(xv.x, w0, acc[r]);
      acc[r] = fmaf(xv.y, w1, acc[r]);
      acc[r] = fmaf(xv.z, w2, acc[r]);
      acc[r] = fmaf(xv.w, w3, acc[r]);
    }
  }
#pragma unroll
  for (int r = 0; r < 32; r++) {
    int row = row0 + r;
    if (row < N_) out[row * H_ + c] = acc[r];
  }
}

// ---------------- fused edge pass ----------------
// alpha = leakyrelu(xl[src]+xr[dst]+ea@We, 0.2) . att ; ae = exp(alpha)
// denom[dst,h] += ae ; agg[dst,c] += ae * xl[src,c]
__global__ __launch_bounds__(256) void edge_kernel(const int* __restrict__ ei,
                                                   const float* __restrict__ ea,
                                                   const float* __restrict__ Wel,
                                                   const float* __restrict__ attl,
                                                   const float* __restrict__ xl,
                                                   const float* __restrict__ xr,
                                                   float* __restrict__ agg,
                                                   float* __restrict__ denom) {
  __shared__ float we_s[8][H_];
  __shared__ float att_s[H_];
  int t = threadIdx.x;
  for (int i = t; i < 8 * H_; i += 256) we_s[i >> 7][i & 127] = Wel[i];
  if (t < H_) att_s[t] = attl[t];
  __syncthreads();
  int lane = t & 127;  // channel
  int sub = t >> 7;    // which edge in pair
  int h = lane >> 5, d = lane & 31;
  for (int e = blockIdx.x * 2 + sub; e < E_; e += gridDim.x * 2) {
    int src = ei[e];
    int dst = ei[E_ + e];
    const float* eav = ea + e * 8;
    float ep = 0.f;
#pragma unroll
    for (int k = 0; k < 8; k++) ep = fmaf(eav[k], we_s[k][lane], ep);
    float xlv = xl[src * H_ + lane];
    float xrv = xr[dst * H_ + lane];
    float m = xlv + xrv + ep;
    m = (m > 0.f) ? m : 0.2f * m;
    float p = m * att_s[lane];
    // butterfly reduce over the 32 lanes of this head (d bits)
#pragma unroll
    for (int off = 16; off > 0; off >>= 1) p += __shfl_xor(p, off, 64);
    float ae = expf(p);
    atomicAdd(&agg[dst * H_ + lane], ae * xlv);
    if (d == 0) atomicAdd(&denom[dst * HEADS_ + h], ae);
  }
}

// ---------------- node post-aggregation: buf = buf/(denom+1e-16) + conv_b ----------------
__global__ __launch_bounds__(256) void node_postagg(float* __restrict__ buf,
                                                    const float* __restrict__ denom,
                                                    const float* __restrict__ cb) {
  int i = blockIdx.x * 256 + threadIdx.x;
  if (i >= N_ * H_) return;
  int c = i & 127;
  int n = i >> 7;
  int h = c >> 5;
  buf[i] = buf[i] / (denom[n * HEADS_ + h] + 1e-16f) + cb[c];
}

// ---------------- column stats (sum, sumsq) for BatchNorm ----------------
__global__ __launch_bounds__(256) void colstats(const float* __restrict__ A, long total, int cmask,
                                                float* __restrict__ ssum, float* __restrict__ ssq) {
  __shared__ float s1[256], s2[256];
  int t = threadIdx.x;
  s1[t] = 0.f;
  s2[t] = 0.f;
  __syncthreads();
  for (long i = (long)blockIdx.x * 256 + t; i < total; i += (long)gridDim.x * 256) {
    float v = A[i];
    int c = (int)i & cmask;
    atomicAdd(&s1[c], v);
    atomicAdd(&s2[c], v * v);
  }
  __syncthreads();
  if (t <= cmask) {
    atomicAdd(&ssum[t], s1[t]);
    atomicAdd(&ssq[t], s2[t]);
  }
}

__global__ void bn_final(const float* __restrict__ ssum, const float* __restrict__ ssq,
                         float rows_inv, int cols, float* __restrict__ mean,
                         float* __restrict__ rstd) {
  int c = threadIdx.x;
  if (c < cols) {
    float m = ssum[c] * rows_inv;
    float v = ssq[c] * rows_inv - m * m;
    mean[c] = m;
    rstd[c] = rsqrtf(v + 1e-5f);
  }
}

// out = relu(g*(y-mean)*rstd + beta)   (out may alias y)
__global__ __launch_bounds__(256) void apply_bn_relu(const float* __restrict__ y,
                                                     float* __restrict__ out,
                                                     const float* __restrict__ g,
                                                     const float* __restrict__ beta,
                                                     const float* __restrict__ mean,
                                                     const float* __restrict__ rstd,
                                                     long total, int cmask) {
  long i = (long)blockIdx.x * 256 + threadIdx.x;
  if (i >= total) return;
  int c = (int)i & cmask;
  float v = g[c] * (y[i] - mean[c]) * rstd[c] + beta[c];
  out[i] = fmaxf(v, 0.f);
}

// xn += elu(g*(buf-mean)*rstd + beta)
__global__ __launch_bounds__(256) void node_residual(float* __restrict__ xn,
                                                     const float* __restrict__ buf,
                                                     const float* __restrict__ g,
                                                     const float* __restrict__ beta,
                                                     const float* __restrict__ mean,
                                                     const float* __restrict__ rstd) {
  int i = blockIdx.x * 256 + threadIdx.x;
  if (i >= N_ * H_) return;
  int c = i & 127;
  float v = g[c] * (buf[i] - mean[c]) * rstd[c] + beta[c];
  v = (v > 0.f) ? v : (expf(v) - 1.f);
  xn[i] += v;
}

// ---------------- pooling ----------------
__global__ __launch_bounds__(256) void init_neginf(float* __restrict__ p, int total) {
  int i = blockIdx.x * 256 + threadIdx.x;
  if (i < total) p[i] = -INFINITY;
}

__global__ __launch_bounds__(256) void pool_kernel(const float* __restrict__ xn,
                                                   const int* __restrict__ batch,
                                                   float* __restrict__ cnt,
                                                   float* __restrict__ sadd,
                                                   float* __restrict__ smax) {
  int i = blockIdx.x * 256 + threadIdx.x;
  if (i >= N_ * H_) return;
  int n = i >> 7;
  int c = i & 127;
  int g = batch[n];
  float v = xn[i];
  atomicAdd(&sadd[g * H_ + c], v);
  atomicMaxF(&smax[g * H_ + c], v);
  if (c == 0) atomicAdd(&cnt[g], 1.f);
}

__global__ __launch_bounds__(256) void xg_assemble(const float* __restrict__ cnt,
                                                   const float* __restrict__ sadd,
                                                   const float* __restrict__ smax,
                                                   float* __restrict__ xg) {
  int i = blockIdx.x * 256 + threadIdx.x;
  if (i >= G_ * H_) return;
  int g = i >> 7;
  int c = i & 127;
  float cv = cnt[g];
  float sa = sadd[i];
  float mx = smax[i];
  xg[g * 384 + c] = sa / fmaxf(cv, 1.f);
  xg[g * 384 + 128 + c] = (cv > 0.f) ? mx : 0.f;
  xg[g * 384 + 256 + c] = sa;
}

// ---------------- MLP GEMMs ----------------
template <int K, int COLS>
__global__ void mlp_gemm(const float* __restrict__ A, const float* __restrict__ W,
                         const float* __restrict__ b, float* __restrict__ Y, int rows) {
  __shared__ float xs[8][K];
  int t = threadIdx.x;  // blockDim == COLS
  int row0 = blockIdx.x * 8;
  for (int i = t; i < 8 * K; i += COLS) {
    int r = i / K, k = i % K;
    int row = row0 + r;
    xs[r][k] = (row < rows) ? A[row * K + k] : 0.f;
  }
  __syncthreads();
  float acc[8];
#pragma unroll
  for (int r = 0; r < 8; r++) acc[r] = 0.f;
  for (int k = 0; k < K; k++) {
    float w = W[k * COLS + t];
#pragma unroll
    for (int r = 0; r < 8; r++) acc[r] = fmaf(xs[r][k], w, acc[r]);
  }
  float bb = b[t];
#pragma unroll
  for (int r = 0; r < 8; r++) {
    int row = row0 + r;
    if (row < rows) Y[row * COLS + t] = acc[r] + bb;
  }
}

// ---------------- head: sigmoid(u2 @ head_W + head_b) ----------------
__global__ __launch_bounds__(64) void head_kernel(const float* __restrict__ u,
                                                  const float* __restrict__ W,
                                                  const float* __restrict__ b,
                                                  float* __restrict__ out) {
  __shared__ float row[128];
  int g = blockIdx.x;
  int t = threadIdx.x;
  row[t] = u[g * 128 + t];
  row[t + 64] = u[g * 128 + 64 + t];
  __syncthreads();
  if (t < 12) {
    float acc = b[t];
    for (int k = 0; k < 128; k++) acc = fmaf(row[k], W[k * 12 + t], acc);
    out[g * 12 + t] = 1.f / (1.f + expf(-acc));
  }
}

// ---------------- launcher ----------------
extern "C" void kernel_launch(void* const* d_in, const int* in_sizes, int n_in, void* d_out,
                              int out_size, void* d_ws, size_t ws_size, hipStream_t stream) {
  (void)in_sizes; (void)n_in; (void)out_size; (void)ws_size;
  const float* x       = (const float*)d_in[0];
  const int*   ei      = (const int*)d_in[1];
  const float* ea      = (const float*)d_in[2];
  const int*   batch   = (const int*)d_in[3];
  const float* in_W    = (const float*)d_in[4];
  const float* in_b    = (const float*)d_in[5];
  const float* in_g    = (const float*)d_in[6];
  const float* in_beta = (const float*)d_in[7];
  const float* Wl      = (const float*)d_in[8];
  const float* Wr      = (const float*)d_in[9];
  const float* We      = (const float*)d_in[10];
  const float* att     = (const float*)d_in[11];
  const float* conv_b  = (const float*)d_in[12];
  const float* bn_g    = (const float*)d_in[13];
  const float* bn_b    = (const float*)d_in[14];
  const float* t1_W    = (const float*)d_in[15];
  const float* t1_b    = (const float*)d_in[16];
  const float* t1_g    = (const float*)d_in[17];
  const float* t1_beta = (const float*)d_in[18];
  const float* t2_W    = (const float*)d_in[19];
  const float* t2_b    = (const float*)d_in[20];
  const float* t2_g    = (const float*)d_in[21];
  const float* t2_beta = (const float*)d_in[22];
  const float* head_W  = (const float*)d_in[23];
  const float* head_b  = (const float*)d_in[24];
  float* out = (float*)d_out;

  // workspace layout (floats), ~111 MB total
  float* p = (float*)d_ws;
  float* xn   = p; p += N_ * H_;
  float* xl   = p; p += N_ * H_;
  float* xr   = p; p += N_ * H_;
  float* buf  = p; p += N_ * H_;        // y0 / agg / hraw (reused)
  float* den  = p; p += N_ * HEADS_;    // contiguous after buf (joint memset)
  float* ssum = p; p += 256;
  float* ssq  = p; p += 256;            // contiguous after ssum (joint memset)
  float* mean = p; p += 256;
  float* rstd = p; p += 256;
  float* cnt  = p; p += G_;
  float* sadd = p; p += G_ * H_;        // contiguous after cnt (joint memset)
  float* smax = p; p += G_ * H_;
  float* xg   = p; p += G_ * 384;
  float* u1   = p; p += G_ * 256;
  float* u2   = p; p += G_ * 128;

  const int EW_GRID = 25000;  // (N*H)/256 elementwise grid

  // ---- input layer ----
  in_gemm<<<N_ / 16, 128, 0, stream>>>(x, in_W, in_b, buf);
  hipMemsetAsync(ssum, 0, 512 * sizeof(float), stream);
  colstats<<<1024, 256, 0, stream>>>(buf, (long)N_ * H_, 127, ssum, ssq);
  bn_final<<<1, 256, 0, stream>>>(ssum, ssq, 1.f / N_, H_, mean, rstd);
  apply_bn_relu<<<EW_GRID, 256, 0, stream>>>(buf, xn, in_g, in_beta, mean, rstd,
                                             (long)N_ * H_, 127);

  // ---- 3 GATv2 layers ----
  for (int l = 0; l < 3; l++) {
    gemm_xlxr<<<(N_ + 31) / 32, 256, 0, stream>>>(xn, Wl + l * H_ * H_, Wr + l * H_ * H_, xl, xr);
    hipMemsetAsync(buf, 0, (size_t)(N_ * H_ + N_ * HEADS_) * sizeof(float), stream);  // buf+den
    edge_kernel<<<8192, 256, 0, stream>>>(ei, ea, We + l * 8 * H_, att + l * HEADS_ * HD_,
                                          xl, xr, buf, den);
    node_postagg<<<EW_GRID, 256, 0, stream>>>(buf, den, conv_b + l * H_);
    hipMemsetAsync(ssum, 0, 512 * sizeof(float), stream);
    colstats<<<1024, 256, 0, stream>>>(buf, (long)N_ * H_, 127, ssum, ssq);
    bn_final<<<1, 256, 0, stream>>>(ssum, ssq, 1.f / N_, H_, mean, rstd);
    node_residual<<<EW_GRID, 256, 0, stream>>>(xn, buf, bn_g + l * H_, bn_b + l * H_, mean, rstd);
  }

  // ---- pooling ----
  hipMemsetAsync(cnt, 0, (size_t)(G_ + G_ * H_) * sizeof(float), stream);  // cnt+sadd
  init_neginf<<<(G_ * H_ + 255) / 256, 256, 0, stream>>>(smax, G_ * H_);
  pool_kernel<<<EW_GRID, 256, 0, stream>>>(xn, batch, cnt, sadd, smax);
  xg_assemble<<<(G_ * H_ + 255) / 256, 256, 0, stream>>>(cnt, sadd, smax, xg);

  // ---- t1 ----
  mlp_gemm<384, 256><<<G_ / 8, 256, 0, stream>>>(xg, t1_W, t1_b, u1, G_);
  hipMemsetAsync(ssum, 0, 512 * sizeof(float), stream);
  colstats<<<256, 256, 0, stream>>>(u1, (long)G_ * 256, 255, ssum, ssq);
  bn_final<<<1, 256, 0, stream>>>(ssum, ssq, 1.f / G_, 256, mean, rstd);
  apply_bn_relu<<<(G_ * 256 + 255) / 256, 256, 0, stream>>>(u1, u1, t1_g, t1_beta, mean, rstd,
                                                            (long)G_ * 256, 255);

  // ---- t2 ----
  mlp_gemm<256, 128><<<G_ / 8, 128, 0, stream>>>(u1, t2_W, t2_b, u2, G_);
  hipMemsetAsync(ssum, 0, 512 * sizeof(float), stream);
  colstats<<<256, 256, 0, stream>>>(u2, (long)G_ * 128, 127, ssum, ssq);
  bn_final<<<1, 256, 0, stream>>>(ssum, ssq, 1.f / G_, 128, mean, rstd);
  apply_bn_relu<<<(G_ * 128 + 255) / 256, 256, 0, stream>>>(u2, u2, t2_g, t2_beta, mean, rstd,
                                                            (long)G_ * 128, 127);

  // ---- head ----
  head_kernel<<<G_, 64, 0, stream>>>(u2, head_W, head_b, out);
}

// Round 2
// 1161.016 us; speedup vs baseline: 1.3962x; 1.3962x over previous
//
#include <hip/hip_runtime.h>
#include <math.h>

// ToxicityGATv2 — round 2: CSR-based edge aggregation (no scatter atomics),
// CSR pooling, register-accumulated colstats, fused BN-stat epilogues.

constexpr int N_ = 50000;
constexpr int E_ = 400000;
constexpr int G_ = 2000;
constexpr int H_ = 128;
constexpr int IN_ = 39;

// ---------------- histogram ----------------
__global__ __launch_bounds__(256) void hist_kernel(const int* __restrict__ keys, int n,
                                                   int* __restrict__ cnt) {
  for (int i = blockIdx.x * 256 + threadIdx.x; i < n; i += gridDim.x * 256)
    atomicAdd(&cnt[keys[i]], 1);
}

// ---------------- single-block exclusive scan (wave-scan based) ----------------
__global__ __launch_bounds__(1024) void scan_excl(const int* __restrict__ in,
                                                  int* __restrict__ out, int n) {
  __shared__ int wsum[16];
  __shared__ int carry_s, chunk_tot;
  int t = threadIdx.x, lane = t & 63, wid = t >> 6;
  if (t == 0) carry_s = 0;
  __syncthreads();
  for (int base = 0; base < n; base += 1024) {
    int idx = base + t;
    int v = (idx < n) ? in[idx] : 0;
    int x = v;
#pragma unroll
    for (int off = 1; off < 64; off <<= 1) {
      int y = __shfl_up(x, off, 64);
      if (lane >= off) x += y;
    }
    if (lane == 63) wsum[wid] = x;
    __syncthreads();
    if (t == 0) {
      int acc = 0;
#pragma unroll
      for (int w = 0; w < 16; w++) { int tmp = wsum[w]; wsum[w] = acc; acc += tmp; }
      chunk_tot = acc;
    }
    __syncthreads();
    if (idx < n) out[idx] = carry_s + wsum[wid] + x - v;
    __syncthreads();
    if (t == 0) carry_s += chunk_tot;
    __syncthreads();
  }
  if (t == 0) out[n] = carry_s;
}

// ---------------- edge scatter into dst-sorted order ----------------
__global__ __launch_bounds__(256) void edge_scatter(const int* __restrict__ ei,
                                                    const float* __restrict__ ea,
                                                    int* __restrict__ cursor,
                                                    int* __restrict__ esrc,
                                                    float* __restrict__ eas) {
  int e = blockIdx.x * 256 + threadIdx.x;
  if (e >= E_) return;
  int src = ei[e];
  int dst = ei[E_ + e];
  int j = atomicAdd(&cursor[dst], 1);
  esrc[j] = src;
  const float4* eav = (const float4*)(ea + (size_t)e * 8);
  float4* dstp = (float4*)(eas + (size_t)j * 8);
  dstp[0] = eav[0];
  dstp[1] = eav[1];
}

// ---------------- input GEMM + fused colstats: y = x@in_W + in_b ----------------
__global__ __launch_bounds__(256) void in_gemm(const float* __restrict__ x,
                                               const float* __restrict__ W,
                                               const float* __restrict__ b,
                                               float* __restrict__ y,
                                               float* __restrict__ ssum,
                                               float* __restrict__ ssq) {
  __shared__ float xs[32][40];
  __shared__ float s1[256], s2[256];
  int t = threadIdx.x;
  int row0 = blockIdx.x * 32;
  for (int i = t; i < 32 * IN_; i += 256) {
    int r = i / IN_, k = i % IN_;
    int row = row0 + r;
    xs[r][k] = (row < N_) ? x[row * IN_ + k] : 0.f;
  }
  __syncthreads();
  int col = t & 127;
  int half = t >> 7;  // rows [half*16, half*16+16)
  float acc[16];
#pragma unroll
  for (int r = 0; r < 16; r++) acc[r] = 0.f;
  for (int k = 0; k < IN_; k++) {
    float w = W[k * H_ + col];
#pragma unroll
    for (int r = 0; r < 16; r++) acc[r] = fmaf(xs[half * 16 + r][k], w, acc[r]);
  }
  float bb = b[col];
  float a1 = 0.f, a2 = 0.f;
#pragma unroll
  for (int r = 0; r < 16; r++) {
    int row = row0 + half * 16 + r;
    float v = acc[r] + bb;
    if (row < N_) {
      y[row * H_ + col] = v;
      a1 += v;
      a2 = fmaf(v, v, a2);
    }
  }
  s1[t] = a1; s2[t] = a2;
  __syncthreads();
  if (t < 128) {
    atomicAdd(&ssum[t], s1[t] + s1[t + 128]);
    atomicAdd(&ssq[t], s2[t] + s2[t + 128]);
  }
}

// ---------------- per-layer node GEMM: xl = xn@Wl, xr = xn@Wr ----------------
__global__ __launch_bounds__(256) void gemm_xlxr(const float* __restrict__ xn,
                                                 const float* __restrict__ Wlp,
                                                 const float* __restrict__ Wrp,
                                                 float* __restrict__ xl,
                                                 float* __restrict__ xr) {
  __shared__ float xs[32][H_];
  int t = threadIdx.x;
  int row0 = blockIdx.x * 32;
  for (int i = t; i < 32 * H_; i += 256) {
    int r = i >> 7, c = i & 127;
    int row = row0 + r;
    xs[r][c] = (row < N_) ? xn[row * H_ + c] : 0.f;
  }
  __syncthreads();
  int c = t & 127;
  const float* W = (t < 128) ? Wlp : Wrp;
  float* out = (t < 128) ? xl : xr;
  float acc[32];
#pragma unroll
  for (int r = 0; r < 32; r++) acc[r] = 0.f;
  for (int k = 0; k < H_; k += 4) {
    float w0 = W[(k + 0) * H_ + c];
    float w1 = W[(k + 1) * H_ + c];
    float w2 = W[(k + 2) * H_ + c];
    float w3 = W[(k + 3) * H_ + c];
#pragma unroll
    for (int r = 0; r < 32; r++) {
      float4 xv = *(const float4*)&xs[r][k];
      acc[r] = fmaf(xv.x, w0, acc[r]);
      acc[r] = fmaf(xv.y, w1, acc[r]);
      acc[r] = fmaf(xv.z, w2, acc[r]);
      acc[r] = fmaf(xv.w, w3, acc[r]);
    }
  }
#pragma unroll
  for (int r = 0; r < 32; r++) {
    int row = row0 + r;
    if (row < N_) out[row * H_ + c] = acc[r];
  }
}

// ---------------- CSR edge aggregation, fused epilogue + colstats ----------------
// For node n: h = sum_e(ae*xl[src]) / (sum_e ae + 1e-16) + conv_b; stats on h.
__global__ __launch_bounds__(256) void agg_csr(const int* __restrict__ eoff,
                                               const int* __restrict__ esrc,
                                               const float* __restrict__ eas,
                                               const float* __restrict__ Wel,
                                               const float* __restrict__ attl,
                                               const float* __restrict__ xl,
                                               const float* __restrict__ xr,
                                               const float* __restrict__ cb,
                                               float* __restrict__ buf,
                                               float* __restrict__ ssum,
                                               float* __restrict__ ssq) {
  __shared__ float we_s[8][H_];
  __shared__ float att_s[H_];
  __shared__ float s1[256], s2[256];
  int t = threadIdx.x;
  for (int i = t; i < 8 * H_; i += 256) we_s[i >> 7][i & 127] = Wel[i];
  if (t < H_) att_s[t] = attl[t];
  __syncthreads();
  int lane = t & 127;
  int sub = t >> 7;
  float cbv = cb[lane];
  float attv = att_s[lane];
  float a1 = 0.f, a2 = 0.f;
  for (int n = blockIdx.x * 2 + sub; n < N_; n += gridDim.x * 2) {
    float xrv = xr[n * H_ + lane];
    int e1 = eoff[n + 1];
    float acc = 0.f, den = 0.f;
    for (int j = eoff[n]; j < e1; j++) {
      int src = esrc[j];
      const float4* eap = (const float4*)(eas + (size_t)j * 8);
      float4 ea0 = eap[0];
      float4 ea1 = eap[1];
      float xlv = xl[src * H_ + lane];
      float ep = ea0.x * we_s[0][lane];
      ep = fmaf(ea0.y, we_s[1][lane], ep);
      ep = fmaf(ea0.z, we_s[2][lane], ep);
      ep = fmaf(ea0.w, we_s[3][lane], ep);
      ep = fmaf(ea1.x, we_s[4][lane], ep);
      ep = fmaf(ea1.y, we_s[5][lane], ep);
      ep = fmaf(ea1.z, we_s[6][lane], ep);
      ep = fmaf(ea1.w, we_s[7][lane], ep);
      float m = xlv + xrv + ep;
      m = (m > 0.f) ? m : 0.2f * m;
      float p = m * attv;
#pragma unroll
      for (int off = 16; off > 0; off >>= 1) p += __shfl_xor(p, off, 64);
      float ae = expf(p);
      acc = fmaf(ae, xlv, acc);
      den += ae;
    }
    float h = acc / (den + 1e-16f) + cbv;
    buf[n * H_ + lane] = h;
    a1 += h;
    a2 = fmaf(h, h, a2);
  }
  s1[t] = a1; s2[t] = a2;
  __syncthreads();
  if (t < 128) {
    atomicAdd(&ssum[t], s1[t] + s1[t + 128]);
    atomicAdd(&ssq[t], s2[t] + s2[t + 128]);
  }
}

// ---------------- colstats (register accumulation) ----------------
// requires (gridDim*256) % (cmask+1) == 0 and 256 % (cmask+1) == 0
__global__ __launch_bounds__(256) void colstats(const float* __restrict__ A, long total,
                                                int cmask, float* __restrict__ ssum,
                                                float* __restrict__ ssq) {
  __shared__ float s1[256], s2[256];
  int t = threadIdx.x;
  float a1 = 0.f, a2 = 0.f;
  for (long i = (long)blockIdx.x * 256 + t; i < total; i += (long)gridDim.x * 256) {
    float v = A[i];
    a1 += v;
    a2 = fmaf(v, v, a2);
  }
  s1[t] = a1; s2[t] = a2;
  __syncthreads();
  if (cmask == 127) {
    if (t < 128) { s1[t] += s1[t + 128]; s2[t] += s2[t + 128]; }
    __syncthreads();
  }
  if (t <= cmask) {
    atomicAdd(&ssum[t], s1[t]);
    atomicAdd(&ssq[t], s2[t]);
  }
}

__global__ void bn_final(const float* __restrict__ ssum, const float* __restrict__ ssq,
                         float rows_inv, int cols, float* __restrict__ mean,
                         float* __restrict__ rstd) {
  int c = threadIdx.x;
  if (c < cols) {
    float m = ssum[c] * rows_inv;
    float v = ssq[c] * rows_inv - m * m;
    mean[c] = m;
    rstd[c] = rsqrtf(v + 1e-5f);
  }
}

// out = relu(g*(y-mean)*rstd + beta)   (out may alias y)
__global__ __launch_bounds__(256) void apply_bn_relu(const float* __restrict__ y,
                                                     float* __restrict__ out,
                                                     const float* __restrict__ g,
                                                     const float* __restrict__ beta,
                                                     const float* __restrict__ mean,
                                                     const float* __restrict__ rstd,
                                                     long total, int cmask) {
  long i = (long)blockIdx.x * 256 + threadIdx.x;
  if (i >= total) return;
  int c = (int)i & cmask;
  float v = g[c] * (y[i] - mean[c]) * rstd[c] + beta[c];
  out[i] = fmaxf(v, 0.f);
}

// xn += elu(g*(buf-mean)*rstd + beta)
__global__ __launch_bounds__(256) void node_residual(float* __restrict__ xn,
                                                     const float* __restrict__ buf,
                                                     const float* __restrict__ g,
                                                     const float* __restrict__ beta,
                                                     const float* __restrict__ mean,
                                                     const float* __restrict__ rstd) {
  int i = blockIdx.x * 256 + threadIdx.x;
  if (i >= N_ * H_) return;
  int c = i & 127;
  float v = g[c] * (buf[i] - mean[c]) * rstd[c] + beta[c];
  v = (v > 0.f) ? v : (expf(v) - 1.f);
  xn[i] += v;
}

// ---------------- CSR pooling: one block per graph ----------------
__global__ __launch_bounds__(128) void pool_csr(const int* __restrict__ goff,
                                                const float* __restrict__ xn,
                                                float* __restrict__ xg) {
  int g = blockIdx.x;
  int t = threadIdx.x;
  int n0 = goff[g], n1 = goff[g + 1];
  float s = 0.f, mx = -INFINITY;
  for (int n = n0; n < n1; n++) {
    float v = xn[n * H_ + t];
    s += v;
    mx = fmaxf(mx, v);
  }
  float c = (float)(n1 - n0);
  xg[g * 384 + t] = s / fmaxf(c, 1.f);
  xg[g * 384 + 128 + t] = (c > 0.f) ? mx : 0.f;
  xg[g * 384 + 256 + t] = s;
}

// ---------------- MLP GEMMs ----------------
template <int K, int COLS>
__global__ void mlp_gemm(const float* __restrict__ A, const float* __restrict__ W,
                         const float* __restrict__ b, float* __restrict__ Y, int rows) {
  __shared__ float xs[8][K];
  int t = threadIdx.x;  // blockDim == COLS
  int row0 = blockIdx.x * 8;
  for (int i = t; i < 8 * K; i += COLS) {
    int r = i / K, k = i % K;
    int row = row0 + r;
    xs[r][k] = (row < rows) ? A[row * K + k] : 0.f;
  }
  __syncthreads();
  float acc[8];
#pragma unroll
  for (int r = 0; r < 8; r++) acc[r] = 0.f;
  for (int k = 0; k < K; k++) {
    float w = W[k * COLS + t];
#pragma unroll
    for (int r = 0; r < 8; r++) acc[r] = fmaf(xs[r][k], w, acc[r]);
  }
  float bb = b[t];
#pragma unroll
  for (int r = 0; r < 8; r++) {
    int row = row0 + r;
    if (row < rows) Y[row * COLS + t] = acc[r] + bb;
  }
}

// ---------------- head: sigmoid(u2 @ head_W + head_b) ----------------
__global__ __launch_bounds__(64) void head_kernel(const float* __restrict__ u,
                                                  const float* __restrict__ W,
                                                  const float* __restrict__ b,
                                                  float* __restrict__ out) {
  __shared__ float row[128];
  int g = blockIdx.x;
  int t = threadIdx.x;
  row[t] = u[g * 128 + t];
  row[t + 64] = u[g * 128 + 64 + t];
  __syncthreads();
  if (t < 12) {
    float acc = b[t];
    for (int k = 0; k < 128; k++) acc = fmaf(row[k], W[k * 12 + t], acc);
    out[g * 12 + t] = 1.f / (1.f + expf(-acc));
  }
}

// ---------------- launcher ----------------
extern "C" void kernel_launch(void* const* d_in, const int* in_sizes, int n_in, void* d_out,
                              int out_size, void* d_ws, size_t ws_size, hipStream_t stream) {
  (void)in_sizes; (void)n_in; (void)out_size; (void)ws_size;
  const float* x       = (const float*)d_in[0];
  const int*   ei      = (const int*)d_in[1];
  const float* ea      = (const float*)d_in[2];
  const int*   batch   = (const int*)d_in[3];
  const float* in_W    = (const float*)d_in[4];
  const float* in_b    = (const float*)d_in[5];
  const float* in_g    = (const float*)d_in[6];
  const float* in_beta = (const float*)d_in[7];
  const float* Wl      = (const float*)d_in[8];
  const float* Wr      = (const float*)d_in[9];
  const float* We      = (const float*)d_in[10];
  const float* att     = (const float*)d_in[11];
  const float* conv_b  = (const float*)d_in[12];
  const float* bn_g    = (const float*)d_in[13];
  const float* bn_b    = (const float*)d_in[14];
  const float* t1_W    = (const float*)d_in[15];
  const float* t1_b    = (const float*)d_in[16];
  const float* t1_g    = (const float*)d_in[17];
  const float* t1_beta = (const float*)d_in[18];
  const float* t2_W    = (const float*)d_in[19];
  const float* t2_b    = (const float*)d_in[20];
  const float* t2_g    = (const float*)d_in[21];
  const float* t2_beta = (const float*)d_in[22];
  const float* head_W  = (const float*)d_in[23];
  const float* head_b  = (const float*)d_in[24];
  float* out = (float*)d_out;

  // workspace layout
  float* p = (float*)d_ws;
  float* xn   = p; p += N_ * H_;
  float* xl   = p; p += N_ * H_;
  float* xr   = p; p += N_ * H_;
  float* buf  = p; p += N_ * H_;
  float* ssum = p; p += 256;
  float* ssq  = p; p += 256;   // contiguous after ssum (joint memset)
  float* mean = p; p += 256;
  float* rstd = p; p += 256;
  float* xg   = p; p += G_ * 384;
  float* u1   = p; p += G_ * 256;
  float* u2   = p; p += G_ * 128;
  float* eas  = p; p += (size_t)E_ * 8;
  int* ip = (int*)p;
  int* deg    = ip; ip += N_;       // deg then gcnt: joint memset
  int* gcnt   = ip; ip += G_;
  int* eoff   = ip; ip += N_ + 1;
  int* cursor = ip; ip += N_;
  int* goff   = ip; ip += G_ + 1;
  int* esrc   = ip; ip += E_;

  const int EW_GRID = 25000;  // (N*H)/256

  // ---- build CSR structures (edges by dst; nodes by graph) ----
  hipMemsetAsync(deg, 0, (size_t)(N_ + G_) * sizeof(int), stream);
  hist_kernel<<<1024, 256, 0, stream>>>(ei + E_, E_, deg);
  scan_excl<<<1, 1024, 0, stream>>>(deg, eoff, N_);
  hipMemcpyAsync(cursor, eoff, (size_t)N_ * sizeof(int), hipMemcpyDeviceToDevice, stream);
  edge_scatter<<<(E_ + 255) / 256, 256, 0, stream>>>(ei, ea, cursor, esrc, eas);
  hist_kernel<<<256, 256, 0, stream>>>(batch, N_, gcnt);
  scan_excl<<<1, 1024, 0, stream>>>(gcnt, goff, G_);

  // ---- input layer ----
  hipMemsetAsync(ssum, 0, 512 * sizeof(float), stream);
  in_gemm<<<(N_ + 31) / 32, 256, 0, stream>>>(x, in_W, in_b, buf, ssum, ssq);
  bn_final<<<1, 256, 0, stream>>>(ssum, ssq, 1.f / N_, H_, mean, rstd);
  apply_bn_relu<<<EW_GRID, 256, 0, stream>>>(buf, xn, in_g, in_beta, mean, rstd,
                                             (long)N_ * H_, 127);

  // ---- 3 GATv2 layers ----
  for (int l = 0; l < 3; l++) {
    gemm_xlxr<<<(N_ + 31) / 32, 256, 0, stream>>>(xn, Wl + l * H_ * H_, Wr + l * H_ * H_, xl, xr);
    hipMemsetAsync(ssum, 0, 512 * sizeof(float), stream);
    agg_csr<<<4096, 256, 0, stream>>>(eoff, esrc, eas, We + l * 8 * H_, att + l * H_,
                                      xl, xr, conv_b + l * H_, buf, ssum, ssq);
    bn_final<<<1, 256, 0, stream>>>(ssum, ssq, 1.f / N_, H_, mean, rstd);
    node_residual<<<EW_GRID, 256, 0, stream>>>(xn, buf, bn_g + l * H_, bn_b + l * H_, mean, rstd);
  }

  // ---- pooling (CSR, no atomics) ----
  pool_csr<<<G_, 128, 0, stream>>>(goff, xn, xg);

  // ---- t1 ----
  mlp_gemm<384, 256><<<G_ / 8, 256, 0, stream>>>(xg, t1_W, t1_b, u1, G_);
  hipMemsetAsync(ssum, 0, 512 * sizeof(float), stream);
  colstats<<<256, 256, 0, stream>>>(u1, (long)G_ * 256, 255, ssum, ssq);
  bn_final<<<1, 256, 0, stream>>>(ssum, ssq, 1.f / G_, 256, mean, rstd);
  apply_bn_relu<<<(G_ * 256 + 255) / 256, 256, 0, stream>>>(u1, u1, t1_g, t1_beta, mean, rstd,
                                                            (long)G_ * 256, 255);

  // ---- t2 ----
  mlp_gemm<256, 128><<<G_ / 8, 128, 0, stream>>>(u1, t2_W, t2_b, u2, G_);
  hipMemsetAsync(ssum, 0, 512 * sizeof(float), stream);
  colstats<<<256, 256, 0, stream>>>(u2, (long)G_ * 128, 127, ssum, ssq);
  bn_final<<<1, 256, 0, stream>>>(ssum, ssq, 1.f / G_, 128, mean, rstd);
  apply_bn_relu<<<(G_ * 128 + 255) / 256, 256, 0, stream>>>(u2, u2, t2_g, t2_beta, mean, rstd,
                                                            (long)G_ * 128, 127);

  // ---- head ----
  head_kernel<<<G_, 64, 0, stream>>>(u2, head_W, head_b, out);
}

// Round 3
// 963.673 us; speedup vs baseline: 1.6821x; 1.2048x over previous
//
#include <hip/hip_runtime.h>
#include <math.h>

// ToxicityGATv2 — round 3: pipelined CSR aggregation (unroll-4 gathers),
// outer-product fp32 node GEMM, direct goff from sorted batch, x4 scan.

constexpr int N_ = 50000;
constexpr int E_ = 400000;
constexpr int G_ = 2000;
constexpr int H_ = 128;
constexpr int IN_ = 39;

// ---------------- histogram ----------------
__global__ __launch_bounds__(256) void hist_kernel(const int* __restrict__ keys, int n,
                                                   int* __restrict__ cnt) {
  for (int i = blockIdx.x * 256 + threadIdx.x; i < n; i += gridDim.x * 256)
    atomicAdd(&cnt[keys[i]], 1);
}

// ---------------- single-block exclusive scan, 4 elems/thread ----------------
__global__ __launch_bounds__(1024) void scan_excl4(const int* __restrict__ in,
                                                   int* __restrict__ out, int n) {
  __shared__ int wsum[16];
  __shared__ int carry_s, chunk_tot;
  int t = threadIdx.x, lane = t & 63, wid = t >> 6;
  if (t == 0) carry_s = 0;
  __syncthreads();
  for (int base = 0; base < n; base += 4096) {
    int idx = base + t * 4;
    int4 v = make_int4(0, 0, 0, 0);
    if (idx + 3 < n) {
      v = *(const int4*)&in[idx];
    } else {
      if (idx < n) v.x = in[idx];
      if (idx + 1 < n) v.y = in[idx + 1];
      if (idx + 2 < n) v.z = in[idx + 2];
      if (idx + 3 < n) v.w = in[idx + 3];
    }
    int tsum = v.x + v.y + v.z + v.w;
    int x = tsum;
#pragma unroll
    for (int off = 1; off < 64; off <<= 1) {
      int y = __shfl_up(x, off, 64);
      if (lane >= off) x += y;
    }
    if (lane == 63) wsum[wid] = x;
    __syncthreads();
    if (t == 0) {
      int acc = 0;
#pragma unroll
      for (int w = 0; w < 16; w++) { int tmp = wsum[w]; wsum[w] = acc; acc += tmp; }
      chunk_tot = acc;
    }
    __syncthreads();
    int base_ex = carry_s + wsum[wid] + x - tsum;
    if (idx < n) out[idx] = base_ex;
    if (idx + 1 < n) out[idx + 1] = base_ex + v.x;
    if (idx + 2 < n) out[idx + 2] = base_ex + v.x + v.y;
    if (idx + 3 < n) out[idx + 3] = base_ex + v.x + v.y + v.z;
    __syncthreads();
    if (t == 0) carry_s += chunk_tot;
    __syncthreads();
  }
  if (t == 0) out[n] = carry_s;
}

// ---------------- goff directly from sorted batch ----------------
__global__ __launch_bounds__(256) void goff_from_sorted(const int* __restrict__ batch,
                                                        int* __restrict__ goff) {
  int i = blockIdx.x * 256 + threadIdx.x;
  if (i >= N_) return;
  int bi = batch[i];
  int bp = (i == 0) ? -1 : batch[i - 1];
  for (int g = bp + 1; g <= bi; g++) goff[g] = i;
  if (i == N_ - 1) {
    for (int g = bi + 1; g <= G_; g++) goff[g] = N_;
  }
}

// ---------------- edge scatter into dst-sorted order ----------------
__global__ __launch_bounds__(256) void edge_scatter(const int* __restrict__ ei,
                                                    const float* __restrict__ ea,
                                                    int* __restrict__ cursor,
                                                    int* __restrict__ esrc,
                                                    float* __restrict__ eas) {
  int e = blockIdx.x * 256 + threadIdx.x;
  if (e >= E_) return;
  int src = ei[e];
  int dst = ei[E_ + e];
  int j = atomicAdd(&cursor[dst], 1);
  esrc[j] = src;
  const float4* eav = (const float4*)(ea + (size_t)e * 8);
  float4* dstp = (float4*)(eas + (size_t)j * 8);
  dstp[0] = eav[0];
  dstp[1] = eav[1];
}

// ---------------- input GEMM + fused colstats ----------------
__global__ __launch_bounds__(256) void in_gemm(const float* __restrict__ x,
                                               const float* __restrict__ W,
                                               const float* __restrict__ b,
                                               float* __restrict__ y,
                                               float* __restrict__ ssum,
                                               float* __restrict__ ssq) {
  __shared__ float xs[32][40];
  __shared__ float s1[256], s2[256];
  int t = threadIdx.x;
  int row0 = blockIdx.x * 32;
  for (int i = t; i < 32 * IN_; i += 256) {
    int r = i / IN_, k = i % IN_;
    int row = row0 + r;
    xs[r][k] = (row < N_) ? x[row * IN_ + k] : 0.f;
  }
  __syncthreads();
  int col = t & 127;
  int half = t >> 7;
  float acc[16];
#pragma unroll
  for (int r = 0; r < 16; r++) acc[r] = 0.f;
  for (int k = 0; k < IN_; k++) {
    float w = W[k * H_ + col];
#pragma unroll
    for (int r = 0; r < 16; r++) acc[r] = fmaf(xs[half * 16 + r][k], w, acc[r]);
  }
  float bb = b[col];
  float a1 = 0.f, a2 = 0.f;
#pragma unroll
  for (int r = 0; r < 16; r++) {
    int row = row0 + half * 16 + r;
    float v = acc[r] + bb;
    if (row < N_) {
      y[row * H_ + col] = v;
      a1 += v;
      a2 = fmaf(v, v, a2);
    }
  }
  s1[t] = a1; s2[t] = a2;
  __syncthreads();
  if (t < 128) {
    atomicAdd(&ssum[t], s1[t] + s1[t + 128]);
    atomicAdd(&ssq[t], s2[t] + s2[t + 128]);
  }
}

// ---------------- node GEMM: xl = xn@Wl, xr = xn@Wr (outer-product tiling) ----
// Tile: 64 rows x 128 cols (x2 outputs). Thread: 8 rows x 4 cols of xl AND xr.
__global__ __launch_bounds__(256) void gemm_xlxr(const float* __restrict__ xn,
                                                 const float* __restrict__ Wlp,
                                                 const float* __restrict__ Wrp,
                                                 float* __restrict__ xl,
                                                 float* __restrict__ xr) {
  __shared__ float xs[64][16];      // 4 KB
  __shared__ float wl_s[16][128];   // 8 KB
  __shared__ float wr_s[16][128];   // 8 KB
  int t = threadIdx.x;
  int tx = t & 31;   // col group: cols tx*4..+3
  int ty = t >> 5;   // row group: rows ty*8..+7
  int row0 = blockIdx.x * 64;
  float4 accl[8], accr[8];
#pragma unroll
  for (int r = 0; r < 8; r++) {
    accl[r] = make_float4(0.f, 0.f, 0.f, 0.f);
    accr[r] = make_float4(0.f, 0.f, 0.f, 0.f);
  }
  for (int kc = 0; kc < H_; kc += 16) {
    __syncthreads();
    {  // stage xs: 64 rows x 16 k
      int r = t >> 2;
      int k4 = (t & 3) * 4;
      int row = row0 + r;
      float4 v = (row < N_) ? *(const float4*)&xn[row * H_ + kc + k4]
                            : make_float4(0.f, 0.f, 0.f, 0.f);
      *(float4*)&xs[r][k4] = v;
    }
    for (int i = t; i < 512; i += 256) {  // stage W tiles: 16 k x 128 c each
      int k = i >> 5;
      int c4 = (i & 31) * 4;
      *(float4*)&wl_s[k][c4] = *(const float4*)&Wlp[(kc + k) * H_ + c4];
      *(float4*)&wr_s[k][c4] = *(const float4*)&Wrp[(kc + k) * H_ + c4];
    }
    __syncthreads();
#pragma unroll
    for (int k = 0; k < 16; k += 4) {
      float4 xv[8];
#pragma unroll
      for (int r = 0; r < 8; r++) xv[r] = *(const float4*)&xs[ty * 8 + r][k];
#pragma unroll
      for (int kk = 0; kk < 4; kk++) {
        float4 wl = *(const float4*)&wl_s[k + kk][tx * 4];
        float4 wr = *(const float4*)&wr_s[k + kk][tx * 4];
#pragma unroll
        for (int r = 0; r < 8; r++) {
          float xvr = (kk == 0) ? xv[r].x : (kk == 1) ? xv[r].y : (kk == 2) ? xv[r].z : xv[r].w;
          accl[r].x = fmaf(xvr, wl.x, accl[r].x);
          accl[r].y = fmaf(xvr, wl.y, accl[r].y);
          accl[r].z = fmaf(xvr, wl.z, accl[r].z);
          accl[r].w = fmaf(xvr, wl.w, accl[r].w);
          accr[r].x = fmaf(xvr, wr.x, accr[r].x);
          accr[r].y = fmaf(xvr, wr.y, accr[r].y);
          accr[r].z = fmaf(xvr, wr.z, accr[r].z);
          accr[r].w = fmaf(xvr, wr.w, accr[r].w);
        }
      }
    }
  }
#pragma unroll
  for (int r = 0; r < 8; r++) {
    int row = row0 + ty * 8 + r;
    if (row < N_) {
      *(float4*)&xl[row * H_ + tx * 4] = accl[r];
      *(float4*)&xr[row * H_ + tx * 4] = accr[r];
    }
  }
}

// ---------------- CSR edge aggregation, pipelined, fused epilogue + colstats ----
__device__ __forceinline__ float epcalc(const float4& a0, const float4& a1, const float w[8]) {
  float ep = a0.x * w[0];
  ep = fmaf(a0.y, w[1], ep);
  ep = fmaf(a0.z, w[2], ep);
  ep = fmaf(a0.w, w[3], ep);
  ep = fmaf(a1.x, w[4], ep);
  ep = fmaf(a1.y, w[5], ep);
  ep = fmaf(a1.z, w[6], ep);
  ep = fmaf(a1.w, w[7], ep);
  return ep;
}

__global__ __launch_bounds__(256) void agg_csr(const int* __restrict__ eoff,
                                               const int* __restrict__ esrc,
                                               const float* __restrict__ eas,
                                               const float* __restrict__ Wel,
                                               const float* __restrict__ attl,
                                               const float* __restrict__ xl,
                                               const float* __restrict__ xr,
                                               const float* __restrict__ cb,
                                               float* __restrict__ buf,
                                               float* __restrict__ ssum,
                                               float* __restrict__ ssq) {
  __shared__ float s1[256], s2[256];
  int t = threadIdx.x;
  int lane = t & 127;
  int sub = t >> 7;
  float w[8];
#pragma unroll
  for (int k = 0; k < 8; k++) w[k] = Wel[k * H_ + lane];
  float attv = attl[lane];
  float cbv = cb[lane];
  float a1 = 0.f, a2 = 0.f;
  for (int n = blockIdx.x * 2 + sub; n < N_; n += gridDim.x * 2) {
    float xrv = xr[n * H_ + lane];
    int e0 = eoff[n], e1 = eoff[n + 1];
    float acc = 0.f, den = 0.f;
    int j = e0;
    for (; j + 4 <= e1; j += 4) {
      int s0 = esrc[j], s1i = esrc[j + 1], s2i = esrc[j + 2], s3 = esrc[j + 3];
      const float4* ep0 = (const float4*)(eas + (size_t)j * 8);
      float4 a00 = ep0[0], a01 = ep0[1];
      float4 a10 = ep0[2], a11 = ep0[3];
      float4 a20 = ep0[4], a21 = ep0[5];
      float4 a30 = ep0[6], a31 = ep0[7];
      float x0 = xl[s0 * H_ + lane];
      float x1 = xl[s1i * H_ + lane];
      float x2 = xl[s2i * H_ + lane];
      float x3 = xl[s3 * H_ + lane];
      float m0 = x0 + xrv + epcalc(a00, a01, w);
      float m1 = x1 + xrv + epcalc(a10, a11, w);
      float m2 = x2 + xrv + epcalc(a20, a21, w);
      float m3 = x3 + xrv + epcalc(a30, a31, w);
      m0 = (m0 > 0.f) ? m0 : 0.2f * m0;
      m1 = (m1 > 0.f) ? m1 : 0.2f * m1;
      m2 = (m2 > 0.f) ? m2 : 0.2f * m2;
      m3 = (m3 > 0.f) ? m3 : 0.2f * m3;
      float p0 = m0 * attv, p1 = m1 * attv, p2 = m2 * attv, p3 = m3 * attv;
#pragma unroll
      for (int off = 16; off > 0; off >>= 1) {
        p0 += __shfl_xor(p0, off, 64);
        p1 += __shfl_xor(p1, off, 64);
        p2 += __shfl_xor(p2, off, 64);
        p3 += __shfl_xor(p3, off, 64);
      }
      float e0v = __expf(p0), e1v = __expf(p1), e2v = __expf(p2), e3v = __expf(p3);
      acc = fmaf(e0v, x0, acc);
      acc = fmaf(e1v, x1, acc);
      acc = fmaf(e2v, x2, acc);
      acc = fmaf(e3v, x3, acc);
      den += (e0v + e1v) + (e2v + e3v);
    }
    for (; j < e1; j++) {
      int src = esrc[j];
      const float4* eap = (const float4*)(eas + (size_t)j * 8);
      float4 ea0 = eap[0], ea1 = eap[1];
      float xlv = xl[src * H_ + lane];
      float m = xlv + xrv + epcalc(ea0, ea1, w);
      m = (m > 0.f) ? m : 0.2f * m;
      float p = m * attv;
#pragma unroll
      for (int off = 16; off > 0; off >>= 1) p += __shfl_xor(p, off, 64);
      float ae = __expf(p);
      acc = fmaf(ae, xlv, acc);
      den += ae;
    }
    float h = acc / (den + 1e-16f) + cbv;
    buf[n * H_ + lane] = h;
    a1 += h;
    a2 = fmaf(h, h, a2);
  }
  s1[t] = a1; s2[t] = a2;
  __syncthreads();
  if (t < 128) {
    atomicAdd(&ssum[t], s1[t] + s1[t + 128]);
    atomicAdd(&ssq[t], s2[t] + s2[t + 128]);
  }
}

__global__ void bn_final(const float* __restrict__ ssum, const float* __restrict__ ssq,
                         float rows_inv, int cols, float* __restrict__ mean,
                         float* __restrict__ rstd) {
  int c = threadIdx.x;
  if (c < cols) {
    float m = ssum[c] * rows_inv;
    float v = ssq[c] * rows_inv - m * m;
    mean[c] = m;
    rstd[c] = rsqrtf(v + 1e-5f);
  }
}

__global__ __launch_bounds__(256) void apply_bn_relu(const float* __restrict__ y,
                                                     float* __restrict__ out,
                                                     const float* __restrict__ g,
                                                     const float* __restrict__ beta,
                                                     const float* __restrict__ mean,
                                                     const float* __restrict__ rstd,
                                                     long total, int cmask) {
  long i = (long)blockIdx.x * 256 + threadIdx.x;
  if (i >= total) return;
  int c = (int)i & cmask;
  float v = g[c] * (y[i] - mean[c]) * rstd[c] + beta[c];
  out[i] = fmaxf(v, 0.f);
}

__global__ __launch_bounds__(256) void node_residual(float* __restrict__ xn,
                                                     const float* __restrict__ buf,
                                                     const float* __restrict__ g,
                                                     const float* __restrict__ beta,
                                                     const float* __restrict__ mean,
                                                     const float* __restrict__ rstd) {
  int i = blockIdx.x * 256 + threadIdx.x;
  if (i >= N_ * H_) return;
  int c = i & 127;
  float v = g[c] * (buf[i] - mean[c]) * rstd[c] + beta[c];
  v = (v > 0.f) ? v : (__expf(v) - 1.f);
  xn[i] += v;
}

// ---------------- CSR pooling ----------------
__global__ __launch_bounds__(128) void pool_csr(const int* __restrict__ goff,
                                                const float* __restrict__ xn,
                                                float* __restrict__ xg) {
  int g = blockIdx.x;
  int t = threadIdx.x;
  int n0 = goff[g], n1 = goff[g + 1];
  float s = 0.f, mx = -INFINITY;
  for (int n = n0; n < n1; n++) {
    float v = xn[n * H_ + t];
    s += v;
    mx = fmaxf(mx, v);
  }
  float c = (float)(n1 - n0);
  xg[g * 384 + t] = s / fmaxf(c, 1.f);
  xg[g * 384 + 128 + t] = (c > 0.f) ? mx : 0.f;
  xg[g * 384 + 256 + t] = s;
}

// ---------------- MLP GEMMs (fused colstats) ----------------
template <int K, int COLS>
__global__ void mlp_gemm(const float* __restrict__ A, const float* __restrict__ W,
                         const float* __restrict__ b, float* __restrict__ Y, int rows,
                         float* __restrict__ ssum, float* __restrict__ ssq) {
  __shared__ float xs[8][K];
  int t = threadIdx.x;  // blockDim == COLS
  int row0 = blockIdx.x * 8;
  for (int i = t; i < 8 * K; i += COLS) {
    int r = i / K, k = i % K;
    int row = row0 + r;
    xs[r][k] = (row < rows) ? A[row * K + k] : 0.f;
  }
  __syncthreads();
  float acc[8];
#pragma unroll
  for (int r = 0; r < 8; r++) acc[r] = 0.f;
  for (int k = 0; k < K; k++) {
    float w = W[k * COLS + t];
#pragma unroll
    for (int r = 0; r < 8; r++) acc[r] = fmaf(xs[r][k], w, acc[r]);
  }
  float bb = b[t];
  float a1 = 0.f, a2 = 0.f;
#pragma unroll
  for (int r = 0; r < 8; r++) {
    int row = row0 + r;
    if (row < rows) {
      float v = acc[r] + bb;
      Y[row * COLS + t] = v;
      a1 += v;
      a2 = fmaf(v, v, a2);
    }
  }
  atomicAdd(&ssum[t], a1);
  atomicAdd(&ssq[t], a2);
}

// ---------------- head ----------------
__global__ __launch_bounds__(64) void head_kernel(const float* __restrict__ u,
                                                  const float* __restrict__ W,
                                                  const float* __restrict__ b,
                                                  float* __restrict__ out) {
  __shared__ float row[128];
  int g = blockIdx.x;
  int t = threadIdx.x;
  row[t] = u[g * 128 + t];
  row[t + 64] = u[g * 128 + 64 + t];
  __syncthreads();
  if (t < 12) {
    float acc = b[t];
    for (int k = 0; k < 128; k++) acc = fmaf(row[k], W[k * 12 + t], acc);
    out[g * 12 + t] = 1.f / (1.f + expf(-acc));
  }
}

// ---------------- launcher ----------------
extern "C" void kernel_launch(void* const* d_in, const int* in_sizes, int n_in, void* d_out,
                              int out_size, void* d_ws, size_t ws_size, hipStream_t stream) {
  (void)in_sizes; (void)n_in; (void)out_size; (void)ws_size;
  const float* x       = (const float*)d_in[0];
  const int*   ei      = (const int*)d_in[1];
  const float* ea      = (const float*)d_in[2];
  const int*   batch   = (const int*)d_in[3];
  const float* in_W    = (const float*)d_in[4];
  const float* in_b    = (const float*)d_in[5];
  const float* in_g    = (const float*)d_in[6];
  const float* in_beta = (const float*)d_in[7];
  const float* Wl      = (const float*)d_in[8];
  const float* Wr      = (const float*)d_in[9];
  const float* We      = (const float*)d_in[10];
  const float* att     = (const float*)d_in[11];
  const float* conv_b  = (const float*)d_in[12];
  const float* bn_g    = (const float*)d_in[13];
  const float* bn_b    = (const float*)d_in[14];
  const float* t1_W    = (const float*)d_in[15];
  const float* t1_b    = (const float*)d_in[16];
  const float* t1_g    = (const float*)d_in[17];
  const float* t1_beta = (const float*)d_in[18];
  const float* t2_W    = (const float*)d_in[19];
  const float* t2_b    = (const float*)d_in[20];
  const float* t2_g    = (const float*)d_in[21];
  const float* t2_beta = (const float*)d_in[22];
  const float* head_W  = (const float*)d_in[23];
  const float* head_b  = (const float*)d_in[24];
  float* out = (float*)d_out;

  float* p = (float*)d_ws;
  float* xn   = p; p += N_ * H_;
  float* xl   = p; p += N_ * H_;
  float* xr   = p; p += N_ * H_;
  float* buf  = p; p += N_ * H_;
  float* ssum = p; p += 256;
  float* ssq  = p; p += 256;   // contiguous after ssum (joint memset)
  float* mean = p; p += 256;
  float* rstd = p; p += 256;
  float* xg   = p; p += G_ * 384;
  float* u1   = p; p += G_ * 256;
  float* u2   = p; p += G_ * 128;
  float* eas  = p; p += (size_t)E_ * 8;
  int* ip = (int*)p;
  int* deg    = ip; ip += N_;
  int* eoff   = ip; ip += N_ + 1;
  int* cursor = ip; ip += N_;
  int* goff   = ip; ip += G_ + 1;
  int* esrc   = ip; ip += E_;

  const int EW_GRID = 25000;  // (N*H)/256

  // ---- build CSR structures ----
  hipMemsetAsync(deg, 0, (size_t)N_ * sizeof(int), stream);
  hist_kernel<<<1024, 256, 0, stream>>>(ei + E_, E_, deg);
  scan_excl4<<<1, 1024, 0, stream>>>(deg, eoff, N_);
  hipMemcpyAsync(cursor, eoff, (size_t)N_ * sizeof(int), hipMemcpyDeviceToDevice, stream);
  edge_scatter<<<(E_ + 255) / 256, 256, 0, stream>>>(ei, ea, cursor, esrc, eas);
  goff_from_sorted<<<(N_ + 255) / 256, 256, 0, stream>>>(batch, goff);

  // ---- input layer ----
  hipMemsetAsync(ssum, 0, 512 * sizeof(float), stream);
  in_gemm<<<(N_ + 31) / 32, 256, 0, stream>>>(x, in_W, in_b, buf, ssum, ssq);
  bn_final<<<1, 256, 0, stream>>>(ssum, ssq, 1.f / N_, H_, mean, rstd);
  apply_bn_relu<<<EW_GRID, 256, 0, stream>>>(buf, xn, in_g, in_beta, mean, rstd,
                                             (long)N_ * H_, 127);

  // ---- 3 GATv2 layers ----
  for (int l = 0; l < 3; l++) {
    gemm_xlxr<<<(N_ + 63) / 64, 256, 0, stream>>>(xn, Wl + l * H_ * H_, Wr + l * H_ * H_, xl, xr);
    hipMemsetAsync(ssum, 0, 512 * sizeof(float), stream);
    agg_csr<<<4096, 256, 0, stream>>>(eoff, esrc, eas, We + l * 8 * H_, att + l * H_,
                                      xl, xr, conv_b + l * H_, buf, ssum, ssq);
    bn_final<<<1, 256, 0, stream>>>(ssum, ssq, 1.f / N_, H_, mean, rstd);
    node_residual<<<EW_GRID, 256, 0, stream>>>(xn, buf, bn_g + l * H_, bn_b + l * H_, mean, rstd);
  }

  // ---- pooling ----
  pool_csr<<<G_, 128, 0, stream>>>(goff, xn, xg);

  // ---- t1 ----
  hipMemsetAsync(ssum, 0, 512 * sizeof(float), stream);
  mlp_gemm<384, 256><<<G_ / 8, 256, 0, stream>>>(xg, t1_W, t1_b, u1, G_, ssum, ssq);
  bn_final<<<1, 256, 0, stream>>>(ssum, ssq, 1.f / G_, 256, mean, rstd);
  apply_bn_relu<<<(G_ * 256 + 255) / 256, 256, 0, stream>>>(u1, u1, t1_g, t1_beta, mean, rstd,
                                                            (long)G_ * 256, 255);

  // ---- t2 ----
  hipMemsetAsync(ssum, 0, 512 * sizeof(float), stream);
  mlp_gemm<256, 128><<<G_ / 8, 128, 0, stream>>>(u1, t2_W, t2_b, u2, G_, ssum, ssq);
  bn_final<<<1, 256, 0, stream>>>(ssum, ssq, 1.f / G_, 128, mean, rstd);
  apply_bn_relu<<<(G_ * 128 + 255) / 256, 256, 0, stream>>>(u2, u2, t2_g, t2_beta, mean, rstd,
                                                            (long)G_ * 128, 127);

  // ---- head ----
  head_kernel<<<G_, 64, 0, stream>>>(u2, head_W, head_b, out);
}

// Round 4
// 911.687 us; speedup vs baseline: 1.7780x; 1.0570x over previous
//
#include <hip/hip_runtime.h>
#include <math.h>

// ToxicityGATv2 — round 4: wave-per-node float2 aggregation (4 node streams/block),
// BN-apply fused into GEMM staging, self-cleaning bn_final, fewer dispatches.

constexpr int N_ = 50000;
constexpr int E_ = 400000;
constexpr int G_ = 2000;
constexpr int H_ = 128;
constexpr int IN_ = 39;

// ---------------- histogram ----------------
__global__ __launch_bounds__(256) void hist_kernel(const int* __restrict__ keys, int n,
                                                   int* __restrict__ cnt) {
  for (int i = blockIdx.x * 256 + threadIdx.x; i < n; i += gridDim.x * 256)
    atomicAdd(&cnt[keys[i]], 1);
}

// ---------------- single-block exclusive scan, 4 elems/thread, dual output ------
__global__ __launch_bounds__(1024) void scan_excl4(const int* __restrict__ in,
                                                   int* __restrict__ out,
                                                   int* __restrict__ out2, int n) {
  __shared__ int wsum[16];
  __shared__ int carry_s, chunk_tot;
  int t = threadIdx.x, lane = t & 63, wid = t >> 6;
  if (t == 0) carry_s = 0;
  __syncthreads();
  for (int base = 0; base < n; base += 4096) {
    int idx = base + t * 4;
    int4 v = make_int4(0, 0, 0, 0);
    if (idx + 3 < n) {
      v = *(const int4*)&in[idx];
    } else {
      if (idx < n) v.x = in[idx];
      if (idx + 1 < n) v.y = in[idx + 1];
      if (idx + 2 < n) v.z = in[idx + 2];
      if (idx + 3 < n) v.w = in[idx + 3];
    }
    int tsum = v.x + v.y + v.z + v.w;
    int x = tsum;
#pragma unroll
    for (int off = 1; off < 64; off <<= 1) {
      int y = __shfl_up(x, off, 64);
      if (lane >= off) x += y;
    }
    if (lane == 63) wsum[wid] = x;
    __syncthreads();
    if (t == 0) {
      int acc = 0;
#pragma unroll
      for (int w = 0; w < 16; w++) { int tmp = wsum[w]; wsum[w] = acc; acc += tmp; }
      chunk_tot = acc;
    }
    __syncthreads();
    int b0 = carry_s + wsum[wid] + x - tsum;
    if (idx < n) { out[idx] = b0; out2[idx] = b0; }
    if (idx + 1 < n) { out[idx + 1] = b0 + v.x; out2[idx + 1] = b0 + v.x; }
    if (idx + 2 < n) { out[idx + 2] = b0 + v.x + v.y; out2[idx + 2] = b0 + v.x + v.y; }
    if (idx + 3 < n) { out[idx + 3] = b0 + v.x + v.y + v.z; out2[idx + 3] = b0 + v.x + v.y + v.z; }
    __syncthreads();
    if (t == 0) carry_s += chunk_tot;
    __syncthreads();
  }
  if (t == 0) out[n] = carry_s;
}

// ---------------- goff directly from sorted batch ----------------
__global__ __launch_bounds__(256) void goff_from_sorted(const int* __restrict__ batch,
                                                        int* __restrict__ goff) {
  int i = blockIdx.x * 256 + threadIdx.x;
  if (i >= N_) return;
  int bi = batch[i];
  int bp = (i == 0) ? -1 : batch[i - 1];
  for (int g = bp + 1; g <= bi; g++) goff[g] = i;
  if (i == N_ - 1) {
    for (int g = bi + 1; g <= G_; g++) goff[g] = N_;
  }
}

// ---------------- edge scatter into dst-sorted order ----------------
__global__ __launch_bounds__(256) void edge_scatter(const int* __restrict__ ei,
                                                    const float* __restrict__ ea,
                                                    int* __restrict__ cursor,
                                                    int* __restrict__ esrc,
                                                    float* __restrict__ eas) {
  int e = blockIdx.x * 256 + threadIdx.x;
  if (e >= E_) return;
  int src = ei[e];
  int dst = ei[E_ + e];
  int j = atomicAdd(&cursor[dst], 1);
  esrc[j] = src;
  const float4* eav = (const float4*)(ea + (size_t)e * 8);
  float4* dstp = (float4*)(eas + (size_t)j * 8);
  dstp[0] = eav[0];
  dstp[1] = eav[1];
}

// ---------------- input GEMM + fused colstats ----------------
__global__ __launch_bounds__(256) void in_gemm(const float* __restrict__ x,
                                               const float* __restrict__ W,
                                               const float* __restrict__ b,
                                               float* __restrict__ y,
                                               float* __restrict__ ssum,
                                               float* __restrict__ ssq) {
  __shared__ float xs[32][40];
  __shared__ float s1[256], s2[256];
  int t = threadIdx.x;
  int row0 = blockIdx.x * 32;
  for (int i = t; i < 32 * IN_; i += 256) {
    int r = i / IN_, k = i % IN_;
    int row = row0 + r;
    xs[r][k] = (row < N_) ? x[row * IN_ + k] : 0.f;
  }
  __syncthreads();
  int col = t & 127;
  int half = t >> 7;
  float acc[16];
#pragma unroll
  for (int r = 0; r < 16; r++) acc[r] = 0.f;
  for (int k = 0; k < IN_; k++) {
    float w = W[k * H_ + col];
#pragma unroll
    for (int r = 0; r < 16; r++) acc[r] = fmaf(xs[half * 16 + r][k], w, acc[r]);
  }
  float bb = b[col];
  float a1 = 0.f, a2 = 0.f;
#pragma unroll
  for (int r = 0; r < 16; r++) {
    int row = row0 + half * 16 + r;
    float v = acc[r] + bb;
    if (row < N_) {
      y[row * H_ + col] = v;
      a1 += v;
      a2 = fmaf(v, v, a2);
    }
  }
  s1[t] = a1; s2[t] = a2;
  __syncthreads();
  if (t < 128) {
    atomicAdd(&ssum[t], s1[t] + s1[t + 128]);
    atomicAdd(&ssq[t], s2[t] + s2[t + 128]);
  }
}

// ---------------- node GEMM with fused BN epilogue in staging ----------------
// MODE 0: xs from xn.  MODE 1: v=relu(bn(buf)); xn=v; xs=v.
// MODE 2: v=xn+elu(bn(buf)); xn=v; xs=v.  (each row tile owned by one block)
template <int MODE>
__global__ __launch_bounds__(256) void gemm_xlxr(const float* __restrict__ xn_ro,
                                                 float* __restrict__ xn,
                                                 const float* __restrict__ buf,
                                                 const float* __restrict__ g,
                                                 const float* __restrict__ beta,
                                                 const float* __restrict__ mean,
                                                 const float* __restrict__ rstd,
                                                 const float* __restrict__ Wlp,
                                                 const float* __restrict__ Wrp,
                                                 float* __restrict__ xl,
                                                 float* __restrict__ xr) {
  __shared__ float xs[64][16];      // 4 KB
  __shared__ float wl_s[16][128];   // 8 KB
  __shared__ float wr_s[16][128];   // 8 KB
  int t = threadIdx.x;
  int tx = t & 31;
  int ty = t >> 5;
  int row0 = blockIdx.x * 64;
  float4 accl[8], accr[8];
#pragma unroll
  for (int r = 0; r < 8; r++) {
    accl[r] = make_float4(0.f, 0.f, 0.f, 0.f);
    accr[r] = make_float4(0.f, 0.f, 0.f, 0.f);
  }
  for (int kc = 0; kc < H_; kc += 16) {
    __syncthreads();
    {  // stage xs: 64 rows x 16 k, fused epilogue
      int r = t >> 2;
      int k4 = (t & 3) * 4;
      int row = row0 + r;
      int c = kc + k4;
      float4 v = make_float4(0.f, 0.f, 0.f, 0.f);
      if (row < N_) {
        if (MODE == 0) {
          v = *(const float4*)&xn_ro[row * H_ + c];
        } else {
          float4 bv = *(const float4*)&buf[row * H_ + c];
          float4 gv = *(const float4*)&g[c];
          float4 be = *(const float4*)&beta[c];
          float4 mn = *(const float4*)&mean[c];
          float4 rs = *(const float4*)&rstd[c];
          float t0 = gv.x * (bv.x - mn.x) * rs.x + be.x;
          float t1 = gv.y * (bv.y - mn.y) * rs.y + be.y;
          float t2 = gv.z * (bv.z - mn.z) * rs.z + be.z;
          float t3 = gv.w * (bv.w - mn.w) * rs.w + be.w;
          if (MODE == 1) {
            v = make_float4(fmaxf(t0, 0.f), fmaxf(t1, 0.f), fmaxf(t2, 0.f), fmaxf(t3, 0.f));
          } else {
            float4 xo = *(const float4*)&xn[row * H_ + c];
            v.x = xo.x + ((t0 > 0.f) ? t0 : (__expf(t0) - 1.f));
            v.y = xo.y + ((t1 > 0.f) ? t1 : (__expf(t1) - 1.f));
            v.z = xo.z + ((t2 > 0.f) ? t2 : (__expf(t2) - 1.f));
            v.w = xo.w + ((t3 > 0.f) ? t3 : (__expf(t3) - 1.f));
          }
          *(float4*)&xn[row * H_ + c] = v;
        }
      }
      *(float4*)&xs[r][k4] = v;
    }
    for (int i = t; i < 512; i += 256) {
      int k = i >> 5;
      int c4 = (i & 31) * 4;
      *(float4*)&wl_s[k][c4] = *(const float4*)&Wlp[(kc + k) * H_ + c4];
      *(float4*)&wr_s[k][c4] = *(const float4*)&Wrp[(kc + k) * H_ + c4];
    }
    __syncthreads();
#pragma unroll
    for (int k = 0; k < 16; k += 4) {
      float4 xv[8];
#pragma unroll
      for (int r = 0; r < 8; r++) xv[r] = *(const float4*)&xs[ty * 8 + r][k];
#pragma unroll
      for (int kk = 0; kk < 4; kk++) {
        float4 wl = *(const float4*)&wl_s[k + kk][tx * 4];
        float4 wr = *(const float4*)&wr_s[k + kk][tx * 4];
#pragma unroll
        for (int r = 0; r < 8; r++) {
          float xvr = (kk == 0) ? xv[r].x : (kk == 1) ? xv[r].y : (kk == 2) ? xv[r].z : xv[r].w;
          accl[r].x = fmaf(xvr, wl.x, accl[r].x);
          accl[r].y = fmaf(xvr, wl.y, accl[r].y);
          accl[r].z = fmaf(xvr, wl.z, accl[r].z);
          accl[r].w = fmaf(xvr, wl.w, accl[r].w);
          accr[r].x = fmaf(xvr, wr.x, accr[r].x);
          accr[r].y = fmaf(xvr, wr.y, accr[r].y);
          accr[r].z = fmaf(xvr, wr.z, accr[r].z);
          accr[r].w = fmaf(xvr, wr.w, accr[r].w);
        }
      }
    }
  }
#pragma unroll
  for (int r = 0; r < 8; r++) {
    int row = row0 + ty * 8 + r;
    if (row < N_) {
      *(float4*)&xl[row * H_ + tx * 4] = accl[r];
      *(float4*)&xr[row * H_ + tx * 4] = accr[r];
    }
  }
}

// ---------------- CSR aggregation: one wave per node, float2 channels/lane -----
__device__ __forceinline__ float ep8(const float4& a0, const float4& a1, const float* w) {
  float ep = a0.x * w[0];
  ep = fmaf(a0.y, w[1], ep);
  ep = fmaf(a0.z, w[2], ep);
  ep = fmaf(a0.w, w[3], ep);
  ep = fmaf(a1.x, w[4], ep);
  ep = fmaf(a1.y, w[5], ep);
  ep = fmaf(a1.z, w[6], ep);
  ep = fmaf(a1.w, w[7], ep);
  return ep;
}

__global__ __launch_bounds__(256) void agg_csr(const int* __restrict__ eoff,
                                               const int* __restrict__ esrc,
                                               const float* __restrict__ eas,
                                               const float* __restrict__ Wel,
                                               const float* __restrict__ attl,
                                               const float* __restrict__ xl,
                                               const float* __restrict__ xr,
                                               const float* __restrict__ cb,
                                               float* __restrict__ buf,
                                               float* __restrict__ ssum,
                                               float* __restrict__ ssq) {
  __shared__ float sA[256], sB[256], sC[256], sD[256];
  int t = threadIdx.x;
  int l = t & 63;    // lane within wave
  int sub = t >> 6;  // node substream 0..3
  int c0 = l * 2;    // channels c0, c0+1 (same head: head = l>>4)
  float w0[8], w1[8];
#pragma unroll
  for (int k = 0; k < 8; k++) {
    float2 wv = *(const float2*)&Wel[k * H_ + c0];
    w0[k] = wv.x; w1[k] = wv.y;
  }
  float2 attv = *(const float2*)&attl[c0];
  float2 cbv = *(const float2*)&cb[c0];
  const float2* xl2 = (const float2*)xl;
  float a1_0 = 0.f, a1_1 = 0.f, a2_0 = 0.f, a2_1 = 0.f;
  for (int n = blockIdx.x * 4 + sub; n < N_; n += gridDim.x * 4) {
    float2 xrv = *(const float2*)&xr[n * H_ + c0];
    int e0 = eoff[n], e1 = eoff[n + 1];
    float acc0 = 0.f, acc1 = 0.f, den = 0.f;
    int j = e0;
    for (; j + 4 <= e1; j += 4) {
      int s0 = esrc[j], s1 = esrc[j + 1], s2 = esrc[j + 2], s3 = esrc[j + 3];
      const float4* ep = (const float4*)(eas + (size_t)j * 8);
      float4 a00 = ep[0], a01 = ep[1];
      float4 a10 = ep[2], a11 = ep[3];
      float4 a20 = ep[4], a21 = ep[5];
      float4 a30 = ep[6], a31 = ep[7];
      float2 x0 = xl2[(size_t)s0 * 64 + l];
      float2 x1 = xl2[(size_t)s1 * 64 + l];
      float2 x2 = xl2[(size_t)s2 * 64 + l];
      float2 x3 = xl2[(size_t)s3 * 64 + l];
      float m00 = x0.x + xrv.x + ep8(a00, a01, w0);
      float m01 = x0.y + xrv.y + ep8(a00, a01, w1);
      float m10 = x1.x + xrv.x + ep8(a10, a11, w0);
      float m11 = x1.y + xrv.y + ep8(a10, a11, w1);
      float m20 = x2.x + xrv.x + ep8(a20, a21, w0);
      float m21 = x2.y + xrv.y + ep8(a20, a21, w1);
      float m30 = x3.x + xrv.x + ep8(a30, a31, w0);
      float m31 = x3.y + xrv.y + ep8(a30, a31, w1);
      m00 = (m00 > 0.f) ? m00 : 0.2f * m00;
      m01 = (m01 > 0.f) ? m01 : 0.2f * m01;
      m10 = (m10 > 0.f) ? m10 : 0.2f * m10;
      m11 = (m11 > 0.f) ? m11 : 0.2f * m11;
      m20 = (m20 > 0.f) ? m20 : 0.2f * m20;
      m21 = (m21 > 0.f) ? m21 : 0.2f * m21;
      m30 = (m30 > 0.f) ? m30 : 0.2f * m30;
      m31 = (m31 > 0.f) ? m31 : 0.2f * m31;
      float p0 = fmaf(m00, attv.x, m01 * attv.y);
      float p1 = fmaf(m10, attv.x, m11 * attv.y);
      float p2 = fmaf(m20, attv.x, m21 * attv.y);
      float p3 = fmaf(m30, attv.x, m31 * attv.y);
#pragma unroll
      for (int off = 8; off > 0; off >>= 1) {
        p0 += __shfl_xor(p0, off, 64);
        p1 += __shfl_xor(p1, off, 64);
        p2 += __shfl_xor(p2, off, 64);
        p3 += __shfl_xor(p3, off, 64);
      }
      float e0v = __expf(p0), e1v = __expf(p1), e2v = __expf(p2), e3v = __expf(p3);
      acc0 = fmaf(e0v, x0.x, acc0); acc1 = fmaf(e0v, x0.y, acc1);
      acc0 = fmaf(e1v, x1.x, acc0); acc1 = fmaf(e1v, x1.y, acc1);
      acc0 = fmaf(e2v, x2.x, acc0); acc1 = fmaf(e2v, x2.y, acc1);
      acc0 = fmaf(e3v, x3.x, acc0); acc1 = fmaf(e3v, x3.y, acc1);
      den += (e0v + e1v) + (e2v + e3v);
    }
    for (; j < e1; j++) {
      int s0 = esrc[j];
      const float4* ep = (const float4*)(eas + (size_t)j * 8);
      float4 a00 = ep[0], a01 = ep[1];
      float2 x0 = xl2[(size_t)s0 * 64 + l];
      float m00 = x0.x + xrv.x + ep8(a00, a01, w0);
      float m01 = x0.y + xrv.y + ep8(a00, a01, w1);
      m00 = (m00 > 0.f) ? m00 : 0.2f * m00;
      m01 = (m01 > 0.f) ? m01 : 0.2f * m01;
      float p0 = fmaf(m00, attv.x, m01 * attv.y);
#pragma unroll
      for (int off = 8; off > 0; off >>= 1) p0 += __shfl_xor(p0, off, 64);
      float e0v = __expf(p0);
      acc0 = fmaf(e0v, x0.x, acc0);
      acc1 = fmaf(e0v, x0.y, acc1);
      den += e0v;
    }
    float inv = 1.f / (den + 1e-16f);
    float h0 = acc0 * inv + cbv.x;
    float h1 = acc1 * inv + cbv.y;
    *(float2*)&buf[n * H_ + c0] = make_float2(h0, h1);
    a1_0 += h0; a1_1 += h1;
    a2_0 = fmaf(h0, h0, a2_0); a2_1 = fmaf(h1, h1, a2_1);
  }
  sA[t] = a1_0; sB[t] = a1_1; sC[t] = a2_0; sD[t] = a2_1;
  __syncthreads();
  if (t < 64) {
    float r1 = sA[t] + sA[t + 64] + sA[t + 128] + sA[t + 192];
    float r2 = sB[t] + sB[t + 64] + sB[t + 128] + sB[t + 192];
    float r3 = sC[t] + sC[t + 64] + sC[t + 128] + sC[t + 192];
    float r4 = sD[t] + sD[t + 64] + sD[t + 128] + sD[t + 192];
    atomicAdd(&ssum[2 * t], r1);
    atomicAdd(&ssum[2 * t + 1], r2);
    atomicAdd(&ssq[2 * t], r3);
    atomicAdd(&ssq[2 * t + 1], r4);
  }
}

// ---------------- bn_final (self-cleaning) ----------------
__global__ void bn_final(float* __restrict__ ssum, float* __restrict__ ssq, float rows_inv,
                         int cols, float* __restrict__ mean, float* __restrict__ rstd) {
  int c = threadIdx.x;
  if (c < cols) {
    float m = ssum[c] * rows_inv;
    float v = ssq[c] * rows_inv - m * m;
    mean[c] = m;
    rstd[c] = rsqrtf(v + 1e-5f);
    ssum[c] = 0.f;
    ssq[c] = 0.f;
  }
}

__global__ __launch_bounds__(256) void apply_bn_relu(const float* __restrict__ y,
                                                     float* __restrict__ out,
                                                     const float* __restrict__ g,
                                                     const float* __restrict__ beta,
                                                     const float* __restrict__ mean,
                                                     const float* __restrict__ rstd,
                                                     long total, int cmask) {
  long i = (long)blockIdx.x * 256 + threadIdx.x;
  if (i >= total) return;
  int c = (int)i & cmask;
  float v = g[c] * (y[i] - mean[c]) * rstd[c] + beta[c];
  out[i] = fmaxf(v, 0.f);
}

__global__ __launch_bounds__(256) void node_residual(float* __restrict__ xn,
                                                     const float* __restrict__ buf,
                                                     const float* __restrict__ g,
                                                     const float* __restrict__ beta,
                                                     const float* __restrict__ mean,
                                                     const float* __restrict__ rstd) {
  int i = blockIdx.x * 256 + threadIdx.x;
  if (i >= N_ * H_) return;
  int c = i & 127;
  float v = g[c] * (buf[i] - mean[c]) * rstd[c] + beta[c];
  v = (v > 0.f) ? v : (__expf(v) - 1.f);
  xn[i] += v;
}

// ---------------- CSR pooling ----------------
__global__ __launch_bounds__(128) void pool_csr(const int* __restrict__ goff,
                                                const float* __restrict__ xn,
                                                float* __restrict__ xg) {
  int g = blockIdx.x;
  int t = threadIdx.x;
  int n0 = goff[g], n1 = goff[g + 1];
  float s = 0.f, mx = -INFINITY;
  for (int n = n0; n < n1; n++) {
    float v = xn[n * H_ + t];
    s += v;
    mx = fmaxf(mx, v);
  }
  float c = (float)(n1 - n0);
  xg[g * 384 + t] = s / fmaxf(c, 1.f);
  xg[g * 384 + 128 + t] = (c > 0.f) ? mx : 0.f;
  xg[g * 384 + 256 + t] = s;
}

// ---------------- MLP GEMMs (fused colstats) ----------------
template <int K, int COLS>
__global__ void mlp_gemm(const float* __restrict__ A, const float* __restrict__ W,
                         const float* __restrict__ b, float* __restrict__ Y, int rows,
                         float* __restrict__ ssum, float* __restrict__ ssq) {
  __shared__ float xs[8][K];
  int t = threadIdx.x;
  int row0 = blockIdx.x * 8;
  for (int i = t; i < 8 * K; i += COLS) {
    int r = i / K, k = i % K;
    int row = row0 + r;
    xs[r][k] = (row < rows) ? A[row * K + k] : 0.f;
  }
  __syncthreads();
  float acc[8];
#pragma unroll
  for (int r = 0; r < 8; r++) acc[r] = 0.f;
  for (int k = 0; k < K; k++) {
    float w = W[k * COLS + t];
#pragma unroll
    for (int r = 0; r < 8; r++) acc[r] = fmaf(xs[r][k], w, acc[r]);
  }
  float bb = b[t];
  float a1 = 0.f, a2 = 0.f;
#pragma unroll
  for (int r = 0; r < 8; r++) {
    int row = row0 + r;
    if (row < rows) {
      float v = acc[r] + bb;
      Y[row * COLS + t] = v;
      a1 += v;
      a2 = fmaf(v, v, a2);
    }
  }
  atomicAdd(&ssum[t], a1);
  atomicAdd(&ssq[t], a2);
}

// ---------------- head ----------------
__global__ __launch_bounds__(64) void head_kernel(const float* __restrict__ u,
                                                  const float* __restrict__ W,
                                                  const float* __restrict__ b,
                                                  float* __restrict__ out) {
  __shared__ float row[128];
  int g = blockIdx.x;
  int t = threadIdx.x;
  row[t] = u[g * 128 + t];
  row[t + 64] = u[g * 128 + 64 + t];
  __syncthreads();
  if (t < 12) {
    float acc = b[t];
    for (int k = 0; k < 128; k++) acc = fmaf(row[k], W[k * 12 + t], acc);
    out[g * 12 + t] = 1.f / (1.f + expf(-acc));
  }
}

// ---------------- launcher ----------------
extern "C" void kernel_launch(void* const* d_in, const int* in_sizes, int n_in, void* d_out,
                              int out_size, void* d_ws, size_t ws_size, hipStream_t stream) {
  (void)in_sizes; (void)n_in; (void)out_size; (void)ws_size;
  const float* x       = (const float*)d_in[0];
  const int*   ei      = (const int*)d_in[1];
  const float* ea      = (const float*)d_in[2];
  const int*   batch   = (const int*)d_in[3];
  const float* in_W    = (const float*)d_in[4];
  const float* in_b    = (const float*)d_in[5];
  const float* in_g    = (const float*)d_in[6];
  const float* in_beta = (const float*)d_in[7];
  const float* Wl      = (const float*)d_in[8];
  const float* Wr      = (const float*)d_in[9];
  const float* We      = (const float*)d_in[10];
  const float* att     = (const float*)d_in[11];
  const float* conv_b  = (const float*)d_in[12];
  const float* bn_g    = (const float*)d_in[13];
  const float* bn_b    = (const float*)d_in[14];
  const float* t1_W    = (const float*)d_in[15];
  const float* t1_b    = (const float*)d_in[16];
  const float* t1_g    = (const float*)d_in[17];
  const float* t1_beta = (const float*)d_in[18];
  const float* t2_W    = (const float*)d_in[19];
  const float* t2_b    = (const float*)d_in[20];
  const float* t2_g    = (const float*)d_in[21];
  const float* t2_beta = (const float*)d_in[22];
  const float* head_W  = (const float*)d_in[23];
  const float* head_b  = (const float*)d_in[24];
  float* out = (float*)d_out;

  float* p = (float*)d_ws;
  float* xn   = p; p += N_ * H_;
  float* xl   = p; p += N_ * H_;
  float* xr   = p; p += N_ * H_;
  float* buf  = p; p += N_ * H_;
  float* ssum = p; p += 256;
  float* ssq  = p; p += 256;   // contiguous after ssum (joint memset)
  float* mean = p; p += 256;
  float* rstd = p; p += 256;
  float* xg   = p; p += G_ * 384;
  float* u1   = p; p += G_ * 256;
  float* u2   = p; p += G_ * 128;
  float* eas  = p; p += (size_t)E_ * 8;
  int* ip = (int*)p;
  int* deg    = ip; ip += N_;
  int* eoff   = ip; ip += N_ + 1;
  int* cursor = ip; ip += N_;
  int* goff   = ip; ip += G_ + 1;
  int* esrc   = ip; ip += E_;

  // ---- build CSR structures ----
  hipMemsetAsync(deg, 0, (size_t)N_ * sizeof(int), stream);
  hist_kernel<<<1024, 256, 0, stream>>>(ei + E_, E_, deg);
  scan_excl4<<<1, 1024, 0, stream>>>(deg, eoff, cursor, N_);
  edge_scatter<<<(E_ + 255) / 256, 256, 0, stream>>>(ei, ea, cursor, esrc, eas);
  goff_from_sorted<<<(N_ + 255) / 256, 256, 0, stream>>>(batch, goff);

  // ---- input layer (stats fused; BN-apply fused into layer-0 GEMM staging) ----
  hipMemsetAsync(ssum, 0, 512 * sizeof(float), stream);
  in_gemm<<<(N_ + 31) / 32, 256, 0, stream>>>(x, in_W, in_b, buf, ssum, ssq);
  bn_final<<<1, 256, 0, stream>>>(ssum, ssq, 1.f / N_, H_, mean, rstd);

  // ---- 3 GATv2 layers ----
  for (int l = 0; l < 3; l++) {
    if (l == 0) {
      gemm_xlxr<1><<<(N_ + 63) / 64, 256, 0, stream>>>(xn, xn, buf, in_g, in_beta, mean, rstd,
                                                       Wl + l * H_ * H_, Wr + l * H_ * H_, xl, xr);
    } else {
      gemm_xlxr<2><<<(N_ + 63) / 64, 256, 0, stream>>>(xn, xn, buf, bn_g + (l - 1) * H_,
                                                       bn_b + (l - 1) * H_, mean, rstd,
                                                       Wl + l * H_ * H_, Wr + l * H_ * H_, xl, xr);
    }
    agg_csr<<<2048, 256, 0, stream>>>(eoff, esrc, eas, We + l * 8 * H_, att + l * H_,
                                      xl, xr, conv_b + l * H_, buf, ssum, ssq);
    bn_final<<<1, 256, 0, stream>>>(ssum, ssq, 1.f / N_, H_, mean, rstd);
  }
  // final residual (layer 2) then pooling
  node_residual<<<25000, 256, 0, stream>>>(xn, buf, bn_g + 2 * H_, bn_b + 2 * H_, mean, rstd);
  pool_csr<<<G_, 128, 0, stream>>>(goff, xn, xg);

  // ---- t1 ----
  mlp_gemm<384, 256><<<G_ / 8, 256, 0, stream>>>(xg, t1_W, t1_b, u1, G_, ssum, ssq);
  bn_final<<<1, 256, 0, stream>>>(ssum, ssq, 1.f / G_, 256, mean, rstd);
  apply_bn_relu<<<(G_ * 256 + 255) / 256, 256, 0, stream>>>(u1, u1, t1_g, t1_beta, mean, rstd,
                                                            (long)G_ * 256, 255);

  // ---- t2 ----
  mlp_gemm<256, 128><<<G_ / 8, 128, 0, stream>>>(u1, t2_W, t2_b, u2, G_, ssum, ssq);
  bn_final<<<1, 256, 0, stream>>>(ssum, ssq, 1.f / G_, 128, mean, rstd);
  apply_bn_relu<<<(G_ * 128 + 255) / 256, 256, 0, stream>>>(u2, u2, t2_g, t2_beta, mean, rstd,
                                                            (long)G_ * 128, 127);

  // ---- head ----
  head_kernel<<<G_, 64, 0, stream>>>(u2, head_W, head_b, out);
}

// Round 5
// 881.162 us; speedup vs baseline: 1.8396x; 1.0346x over previous
//
#include <hip/hip_runtime.h>
#include <math.h>

// ToxicityGATv2 — round 5: bf16-compressed edge path (xl/xr/eas), multi-block
// scan, residual fused into pooling. All arithmetic fp32; storage bf16 where
// it only perturbs values within the bf16-derived absmax threshold.

constexpr int N_ = 50000;
constexpr int E_ = 400000;
constexpr int G_ = 2000;
constexpr int H_ = 128;
constexpr int IN_ = 39;

// ---------------- bf16 pack/unpack (RNE) ----------------
__device__ __forceinline__ unsigned pk_bf16(float a, float b) {
  unsigned ua = __float_as_uint(a);
  unsigned ub = __float_as_uint(b);
  ua = (ua + 0x7fffu + ((ua >> 16) & 1u)) >> 16;
  ub = (ub + 0x7fffu + ((ub >> 16) & 1u)) & 0xffff0000u;
  return ua | ub;
}
__device__ __forceinline__ float up_lo(unsigned u) { return __uint_as_float(u << 16); }
__device__ __forceinline__ float up_hi(unsigned u) { return __uint_as_float(u & 0xffff0000u); }

// ---------------- histogram ----------------
__global__ __launch_bounds__(256) void hist_kernel(const int* __restrict__ keys, int n,
                                                   int* __restrict__ cnt) {
  for (int i = blockIdx.x * 256 + threadIdx.x; i < n; i += gridDim.x * 256)
    atomicAdd(&cnt[keys[i]], 1);
}

// ---------------- multi-block scan: local pass ----------------
__global__ __launch_bounds__(1024) void scan_local(const int* __restrict__ in,
                                                   int* __restrict__ outx,
                                                   int* __restrict__ bsum, int n) {
  __shared__ int wsum[16];
  int t = threadIdx.x, lane = t & 63, wid = t >> 6;
  int idx = blockIdx.x * 1024 + t;
  int v = (idx < n) ? in[idx] : 0;
  int x = v;
#pragma unroll
  for (int off = 1; off < 64; off <<= 1) {
    int y = __shfl_up(x, off, 64);
    if (lane >= off) x += y;
  }
  if (lane == 63) wsum[wid] = x;
  __syncthreads();
  if (t == 0) {
    int acc = 0;
#pragma unroll
    for (int w = 0; w < 16; w++) { int tmp = wsum[w]; wsum[w] = acc; acc += tmp; }
    bsum[blockIdx.x] = acc;
  }
  __syncthreads();
  if (idx < n) outx[idx] = wsum[wid] + x - v;
}

// ---------------- scan of block sums (<=64 blocks, 1 wave) ----------------
__global__ __launch_bounds__(64) void scan_bsum(const int* __restrict__ bsum,
                                                int* __restrict__ boff, int nb) {
  int t = threadIdx.x;
  int v = (t < nb) ? bsum[t] : 0;
  int x = v;
#pragma unroll
  for (int off = 1; off < 64; off <<= 1) {
    int y = __shfl_up(x, off, 64);
    if (t >= off) x += y;
  }
  boff[t] = x - v;  // exclusive
}

__global__ __launch_bounds__(1024) void scan_add(int* __restrict__ eoff,
                                                 const int* __restrict__ boff,
                                                 int* __restrict__ cursor, int n) {
  int idx = blockIdx.x * 1024 + threadIdx.x;
  if (idx < n) {
    int e = eoff[idx] + boff[idx >> 10];
    eoff[idx] = e;
    cursor[idx] = e;
  }
  if (idx == 0) eoff[n] = E_;
}

// ---------------- goff directly from sorted batch ----------------
__global__ __launch_bounds__(256) void goff_from_sorted(const int* __restrict__ batch,
                                                        int* __restrict__ goff) {
  int i = blockIdx.x * 256 + threadIdx.x;
  if (i >= N_) return;
  int bi = batch[i];
  int bp = (i == 0) ? -1 : batch[i - 1];
  for (int g = bp + 1; g <= bi; g++) goff[g] = i;
  if (i == N_ - 1) {
    for (int g = bi + 1; g <= G_; g++) goff[g] = N_;
  }
}

// ---------------- edge scatter into dst-sorted order (bf16 attrs) ----------------
__global__ __launch_bounds__(256) void edge_scatter(const int* __restrict__ ei,
                                                    const float* __restrict__ ea,
                                                    int* __restrict__ cursor,
                                                    int* __restrict__ esrc,
                                                    unsigned* __restrict__ easb) {
  int e = blockIdx.x * 256 + threadIdx.x;
  if (e >= E_) return;
  int src = ei[e];
  int dst = ei[E_ + e];
  int j = atomicAdd(&cursor[dst], 1);
  esrc[j] = src;
  const float4* eav = (const float4*)(ea + (size_t)e * 8);
  float4 a0 = eav[0], a1 = eav[1];
  uint4 o;
  o.x = pk_bf16(a0.x, a0.y);
  o.y = pk_bf16(a0.z, a0.w);
  o.z = pk_bf16(a1.x, a1.y);
  o.w = pk_bf16(a1.z, a1.w);
  ((uint4*)easb)[j] = o;
}

// ---------------- input GEMM + fused colstats ----------------
__global__ __launch_bounds__(256) void in_gemm(const float* __restrict__ x,
                                               const float* __restrict__ W,
                                               const float* __restrict__ b,
                                               float* __restrict__ y,
                                               float* __restrict__ ssum,
                                               float* __restrict__ ssq) {
  __shared__ float xs[32][40];
  __shared__ float s1[256], s2[256];
  int t = threadIdx.x;
  int row0 = blockIdx.x * 32;
  for (int i = t; i < 32 * IN_; i += 256) {
    int r = i / IN_, k = i % IN_;
    int row = row0 + r;
    xs[r][k] = (row < N_) ? x[row * IN_ + k] : 0.f;
  }
  __syncthreads();
  int col = t & 127;
  int half = t >> 7;
  float acc[16];
#pragma unroll
  for (int r = 0; r < 16; r++) acc[r] = 0.f;
  for (int k = 0; k < IN_; k++) {
    float w = W[k * H_ + col];
#pragma unroll
    for (int r = 0; r < 16; r++) acc[r] = fmaf(xs[half * 16 + r][k], w, acc[r]);
  }
  float bb = b[col];
  float a1 = 0.f, a2 = 0.f;
#pragma unroll
  for (int r = 0; r < 16; r++) {
    int row = row0 + half * 16 + r;
    float v = acc[r] + bb;
    if (row < N_) {
      y[row * H_ + col] = v;
      a1 += v;
      a2 = fmaf(v, v, a2);
    }
  }
  s1[t] = a1; s2[t] = a2;
  __syncthreads();
  if (t < 128) {
    atomicAdd(&ssum[t], s1[t] + s1[t + 128]);
    atomicAdd(&ssq[t], s2[t] + s2[t + 128]);
  }
}

// ---------------- node GEMM with fused BN epilogue; bf16 packed outputs --------
// MODE 1: v=relu(bn(buf)); xn=v; xs=v.   MODE 2: v=xn+elu(bn(buf)); xn=v; xs=v.
template <int MODE>
__global__ __launch_bounds__(256) void gemm_xlxr(const float* __restrict__ xn_ro,
                                                 float* __restrict__ xn,
                                                 const float* __restrict__ buf,
                                                 const float* __restrict__ g,
                                                 const float* __restrict__ beta,
                                                 const float* __restrict__ mean,
                                                 const float* __restrict__ rstd,
                                                 const float* __restrict__ Wlp,
                                                 const float* __restrict__ Wrp,
                                                 unsigned* __restrict__ xlb,
                                                 unsigned* __restrict__ xrb) {
  __shared__ float xs[64][16];
  __shared__ float wl_s[16][128];
  __shared__ float wr_s[16][128];
  int t = threadIdx.x;
  int tx = t & 31;
  int ty = t >> 5;
  int row0 = blockIdx.x * 64;
  float4 accl[8], accr[8];
#pragma unroll
  for (int r = 0; r < 8; r++) {
    accl[r] = make_float4(0.f, 0.f, 0.f, 0.f);
    accr[r] = make_float4(0.f, 0.f, 0.f, 0.f);
  }
  for (int kc = 0; kc < H_; kc += 16) {
    __syncthreads();
    {
      int r = t >> 2;
      int k4 = (t & 3) * 4;
      int row = row0 + r;
      int c = kc + k4;
      float4 v = make_float4(0.f, 0.f, 0.f, 0.f);
      if (row < N_) {
        if (MODE == 0) {
          v = *(const float4*)&xn_ro[row * H_ + c];
        } else {
          float4 bv = *(const float4*)&buf[row * H_ + c];
          float4 gv = *(const float4*)&g[c];
          float4 be = *(const float4*)&beta[c];
          float4 mn = *(const float4*)&mean[c];
          float4 rs = *(const float4*)&rstd[c];
          float t0 = gv.x * (bv.x - mn.x) * rs.x + be.x;
          float t1 = gv.y * (bv.y - mn.y) * rs.y + be.y;
          float t2 = gv.z * (bv.z - mn.z) * rs.z + be.z;
          float t3 = gv.w * (bv.w - mn.w) * rs.w + be.w;
          if (MODE == 1) {
            v = make_float4(fmaxf(t0, 0.f), fmaxf(t1, 0.f), fmaxf(t2, 0.f), fmaxf(t3, 0.f));
          } else {
            float4 xo = *(const float4*)&xn[row * H_ + c];
            v.x = xo.x + ((t0 > 0.f) ? t0 : (__expf(t0) - 1.f));
            v.y = xo.y + ((t1 > 0.f) ? t1 : (__expf(t1) - 1.f));
            v.z = xo.z + ((t2 > 0.f) ? t2 : (__expf(t2) - 1.f));
            v.w = xo.w + ((t3 > 0.f) ? t3 : (__expf(t3) - 1.f));
          }
          *(float4*)&xn[row * H_ + c] = v;
        }
      }
      *(float4*)&xs[r][k4] = v;
    }
    for (int i = t; i < 512; i += 256) {
      int k = i >> 5;
      int c4 = (i & 31) * 4;
      *(float4*)&wl_s[k][c4] = *(const float4*)&Wlp[(kc + k) * H_ + c4];
      *(float4*)&wr_s[k][c4] = *(const float4*)&Wrp[(kc + k) * H_ + c4];
    }
    __syncthreads();
#pragma unroll
    for (int k = 0; k < 16; k += 4) {
      float4 xv[8];
#pragma unroll
      for (int r = 0; r < 8; r++) xv[r] = *(const float4*)&xs[ty * 8 + r][k];
#pragma unroll
      for (int kk = 0; kk < 4; kk++) {
        float4 wl = *(const float4*)&wl_s[k + kk][tx * 4];
        float4 wr = *(const float4*)&wr_s[k + kk][tx * 4];
#pragma unroll
        for (int r = 0; r < 8; r++) {
          float xvr = (kk == 0) ? xv[r].x : (kk == 1) ? xv[r].y : (kk == 2) ? xv[r].z : xv[r].w;
          accl[r].x = fmaf(xvr, wl.x, accl[r].x);
          accl[r].y = fmaf(xvr, wl.y, accl[r].y);
          accl[r].z = fmaf(xvr, wl.z, accl[r].z);
          accl[r].w = fmaf(xvr, wl.w, accl[r].w);
          accr[r].x = fmaf(xvr, wr.x, accr[r].x);
          accr[r].y = fmaf(xvr, wr.y, accr[r].y);
          accr[r].z = fmaf(xvr, wr.z, accr[r].z);
          accr[r].w = fmaf(xvr, wr.w, accr[r].w);
        }
      }
    }
  }
#pragma unroll
  for (int r = 0; r < 8; r++) {
    int row = row0 + ty * 8 + r;
    if (row < N_) {
      uint2 ul, ur;
      ul.x = pk_bf16(accl[r].x, accl[r].y);
      ul.y = pk_bf16(accl[r].z, accl[r].w);
      ur.x = pk_bf16(accr[r].x, accr[r].y);
      ur.y = pk_bf16(accr[r].z, accr[r].w);
      *(uint2*)&xlb[(size_t)row * 64 + tx * 2] = ul;
      *(uint2*)&xrb[(size_t)row * 64 + tx * 2] = ur;
    }
  }
}

// ---------------- CSR aggregation: wave/node, bf16 gathers -------------------
__device__ __forceinline__ float ep8u(const uint4& u, const float* w) {
  float ep = up_lo(u.x) * w[0];
  ep = fmaf(up_hi(u.x), w[1], ep);
  ep = fmaf(up_lo(u.y), w[2], ep);
  ep = fmaf(up_hi(u.y), w[3], ep);
  ep = fmaf(up_lo(u.z), w[4], ep);
  ep = fmaf(up_hi(u.z), w[5], ep);
  ep = fmaf(up_lo(u.w), w[6], ep);
  ep = fmaf(up_hi(u.w), w[7], ep);
  return ep;
}

__global__ __launch_bounds__(256) void agg_csr(const int* __restrict__ eoff,
                                               const int* __restrict__ esrc,
                                               const unsigned* __restrict__ easb,
                                               const float* __restrict__ Wel,
                                               const float* __restrict__ attl,
                                               const unsigned* __restrict__ xlb,
                                               const unsigned* __restrict__ xrb,
                                               const float* __restrict__ cb,
                                               float* __restrict__ buf,
                                               float* __restrict__ ssum,
                                               float* __restrict__ ssq) {
  __shared__ float sA[256], sB[256], sC[256], sD[256];
  int t = threadIdx.x;
  int l = t & 63;
  int sub = t >> 6;
  int c0 = l * 2;
  float w0[8], w1[8];
#pragma unroll
  for (int k = 0; k < 8; k++) {
    float2 wv = *(const float2*)&Wel[k * H_ + c0];
    w0[k] = wv.x; w1[k] = wv.y;
  }
  float2 attv = *(const float2*)&attl[c0];
  float2 cbv = *(const float2*)&cb[c0];
  const uint4* eas4 = (const uint4*)easb;
  float a1_0 = 0.f, a1_1 = 0.f, a2_0 = 0.f, a2_1 = 0.f;
  for (int n = blockIdx.x * 4 + sub; n < N_; n += gridDim.x * 4) {
    unsigned xru = xrb[(size_t)n * 64 + l];
    float xr0 = up_lo(xru), xr1 = up_hi(xru);
    int e0 = eoff[n], e1 = eoff[n + 1];
    float acc0 = 0.f, acc1 = 0.f, den = 0.f;
    int j = e0;
    for (; j + 4 <= e1; j += 4) {
      int s0 = esrc[j], s1 = esrc[j + 1], s2 = esrc[j + 2], s3 = esrc[j + 3];
      uint4 u0 = eas4[j], u1 = eas4[j + 1], u2 = eas4[j + 2], u3 = eas4[j + 3];
      unsigned xu0 = xlb[(size_t)s0 * 64 + l];
      unsigned xu1 = xlb[(size_t)s1 * 64 + l];
      unsigned xu2 = xlb[(size_t)s2 * 64 + l];
      unsigned xu3 = xlb[(size_t)s3 * 64 + l];
      float x00 = up_lo(xu0), x01 = up_hi(xu0);
      float x10 = up_lo(xu1), x11 = up_hi(xu1);
      float x20 = up_lo(xu2), x21 = up_hi(xu2);
      float x30 = up_lo(xu3), x31 = up_hi(xu3);
      float m00 = x00 + xr0 + ep8u(u0, w0);
      float m01 = x01 + xr1 + ep8u(u0, w1);
      float m10 = x10 + xr0 + ep8u(u1, w0);
      float m11 = x11 + xr1 + ep8u(u1, w1);
      float m20 = x20 + xr0 + ep8u(u2, w0);
      float m21 = x21 + xr1 + ep8u(u2, w1);
      float m30 = x30 + xr0 + ep8u(u3, w0);
      float m31 = x31 + xr1 + ep8u(u3, w1);
      m00 = (m00 > 0.f) ? m00 : 0.2f * m00;
      m01 = (m01 > 0.f) ? m01 : 0.2f * m01;
      m10 = (m10 > 0.f) ? m10 : 0.2f * m10;
      m11 = (m11 > 0.f) ? m11 : 0.2f * m11;
      m20 = (m20 > 0.f) ? m20 : 0.2f * m20;
      m21 = (m21 > 0.f) ? m21 : 0.2f * m21;
      m30 = (m30 > 0.f) ? m30 : 0.2f * m30;
      m31 = (m31 > 0.f) ? m31 : 0.2f * m31;
      float p0 = fmaf(m00, attv.x, m01 * attv.y);
      float p1 = fmaf(m10, attv.x, m11 * attv.y);
      float p2 = fmaf(m20, attv.x, m21 * attv.y);
      float p3 = fmaf(m30, attv.x, m31 * attv.y);
#pragma unroll
      for (int off = 8; off > 0; off >>= 1) {
        p0 += __shfl_xor(p0, off, 64);
        p1 += __shfl_xor(p1, off, 64);
        p2 += __shfl_xor(p2, off, 64);
        p3 += __shfl_xor(p3, off, 64);
      }
      float e0v = __expf(p0), e1v = __expf(p1), e2v = __expf(p2), e3v = __expf(p3);
      acc0 = fmaf(e0v, x00, acc0); acc1 = fmaf(e0v, x01, acc1);
      acc0 = fmaf(e1v, x10, acc0); acc1 = fmaf(e1v, x11, acc1);
      acc0 = fmaf(e2v, x20, acc0); acc1 = fmaf(e2v, x21, acc1);
      acc0 = fmaf(e3v, x30, acc0); acc1 = fmaf(e3v, x31, acc1);
      den += (e0v + e1v) + (e2v + e3v);
    }
    for (; j < e1; j++) {
      int s0 = esrc[j];
      uint4 u0 = eas4[j];
      unsigned xu0 = xlb[(size_t)s0 * 64 + l];
      float x00 = up_lo(xu0), x01 = up_hi(xu0);
      float m00 = x00 + xr0 + ep8u(u0, w0);
      float m01 = x01 + xr1 + ep8u(u0, w1);
      m00 = (m00 > 0.f) ? m00 : 0.2f * m00;
      m01 = (m01 > 0.f) ? m01 : 0.2f * m01;
      float p0 = fmaf(m00, attv.x, m01 * attv.y);
#pragma unroll
      for (int off = 8; off > 0; off >>= 1) p0 += __shfl_xor(p0, off, 64);
      float e0v = __expf(p0);
      acc0 = fmaf(e0v, x00, acc0);
      acc1 = fmaf(e0v, x01, acc1);
      den += e0v;
    }
    float inv = 1.f / (den + 1e-16f);
    float h0 = acc0 * inv + cbv.x;
    float h1 = acc1 * inv + cbv.y;
    *(float2*)&buf[(size_t)n * H_ + c0] = make_float2(h0, h1);
    a1_0 += h0; a1_1 += h1;
    a2_0 = fmaf(h0, h0, a2_0); a2_1 = fmaf(h1, h1, a2_1);
  }
  sA[t] = a1_0; sB[t] = a1_1; sC[t] = a2_0; sD[t] = a2_1;
  __syncthreads();
  if (t < 64) {
    float r1 = sA[t] + sA[t + 64] + sA[t + 128] + sA[t + 192];
    float r2 = sB[t] + sB[t + 64] + sB[t + 128] + sB[t + 192];
    float r3 = sC[t] + sC[t + 64] + sC[t + 128] + sC[t + 192];
    float r4 = sD[t] + sD[t + 64] + sD[t + 128] + sD[t + 192];
    atomicAdd(&ssum[2 * t], r1);
    atomicAdd(&ssum[2 * t + 1], r2);
    atomicAdd(&ssq[2 * t], r3);
    atomicAdd(&ssq[2 * t + 1], r4);
  }
}

// ---------------- bn_final (always cleans all 256 slots) ----------------
__global__ void bn_final(float* __restrict__ ssum, float* __restrict__ ssq, float rows_inv,
                         int cols, float* __restrict__ mean, float* __restrict__ rstd) {
  int c = threadIdx.x;
  if (c < cols) {
    float m = ssum[c] * rows_inv;
    float v = ssq[c] * rows_inv - m * m;
    mean[c] = m;
    rstd[c] = rsqrtf(v + 1e-5f);
  }
  ssum[c] = 0.f;
  ssq[c] = 0.f;
}

__global__ __launch_bounds__(256) void apply_bn_relu(const float* __restrict__ y,
                                                     float* __restrict__ out,
                                                     const float* __restrict__ g,
                                                     const float* __restrict__ beta,
                                                     const float* __restrict__ mean,
                                                     const float* __restrict__ rstd,
                                                     long total, int cmask) {
  long i = (long)blockIdx.x * 256 + threadIdx.x;
  if (i >= total) return;
  int c = (int)i & cmask;
  float v = g[c] * (y[i] - mean[c]) * rstd[c] + beta[c];
  out[i] = fmaxf(v, 0.f);
}

// ---------------- pooling with fused layer-2 residual ----------------
// v = xn + elu(bn(buf)); reduce sum/max per graph; xn not written back.
__global__ __launch_bounds__(128) void pool_residual(const int* __restrict__ goff,
                                                     const float* __restrict__ xn,
                                                     const float* __restrict__ buf,
                                                     const float* __restrict__ g,
                                                     const float* __restrict__ beta,
                                                     const float* __restrict__ mean,
                                                     const float* __restrict__ rstd,
                                                     float* __restrict__ xg) {
  int gr = blockIdx.x;
  int t = threadIdx.x;
  int n0 = goff[gr], n1 = goff[gr + 1];
  float gg = g[t], bb = beta[t], mm = mean[t], rr = rstd[t];
  float s = 0.f, mx = -INFINITY;
  for (int n = n0; n < n1; n++) {
    float w = gg * (buf[(size_t)n * H_ + t] - mm) * rr + bb;
    w = (w > 0.f) ? w : (__expf(w) - 1.f);
    float v = xn[(size_t)n * H_ + t] + w;
    s += v;
    mx = fmaxf(mx, v);
  }
  float c = (float)(n1 - n0);
  xg[gr * 384 + t] = s / fmaxf(c, 1.f);
  xg[gr * 384 + 128 + t] = (c > 0.f) ? mx : 0.f;
  xg[gr * 384 + 256 + t] = s;
}

// ---------------- MLP GEMMs (fused colstats) ----------------
template <int K, int COLS>
__global__ void mlp_gemm(const float* __restrict__ A, const float* __restrict__ W,
                         const float* __restrict__ b, float* __restrict__ Y, int rows,
                         float* __restrict__ ssum, float* __restrict__ ssq) {
  __shared__ float xs[8][K];
  int t = threadIdx.x;
  int row0 = blockIdx.x * 8;
  for (int i = t; i < 8 * K; i += COLS) {
    int r = i / K, k = i % K;
    int row = row0 + r;
    xs[r][k] = (row < rows) ? A[row * K + k] : 0.f;
  }
  __syncthreads();
  float acc[8];
#pragma unroll
  for (int r = 0; r < 8; r++) acc[r] = 0.f;
  for (int k = 0; k < K; k++) {
    float w = W[k * COLS + t];
#pragma unroll
    for (int r = 0; r < 8; r++) acc[r] = fmaf(xs[r][k], w, acc[r]);
  }
  float bb = b[t];
  float a1 = 0.f, a2 = 0.f;
#pragma unroll
  for (int r = 0; r < 8; r++) {
    int row = row0 + r;
    if (row < rows) {
      float v = acc[r] + bb;
      Y[row * COLS + t] = v;
      a1 += v;
      a2 = fmaf(v, v, a2);
    }
  }
  atomicAdd(&ssum[t], a1);
  atomicAdd(&ssq[t], a2);
}

// ---------------- head ----------------
__global__ __launch_bounds__(64) void head_kernel(const float* __restrict__ u,
                                                  const float* __restrict__ W,
                                                  const float* __restrict__ b,
                                                  float* __restrict__ out) {
  __shared__ float row[128];
  int g = blockIdx.x;
  int t = threadIdx.x;
  row[t] = u[g * 128 + t];
  row[t + 64] = u[g * 128 + 64 + t];
  __syncthreads();
  if (t < 12) {
    float acc = b[t];
    for (int k = 0; k < 128; k++) acc = fmaf(row[k], W[k * 12 + t], acc);
    out[g * 12 + t] = 1.f / (1.f + expf(-acc));
  }
}

// ---------------- launcher ----------------
extern "C" void kernel_launch(void* const* d_in, const int* in_sizes, int n_in, void* d_out,
                              int out_size, void* d_ws, size_t ws_size, hipStream_t stream) {
  (void)in_sizes; (void)n_in; (void)out_size; (void)ws_size;
  const float* x       = (const float*)d_in[0];
  const int*   ei      = (const int*)d_in[1];
  const float* ea      = (const float*)d_in[2];
  const int*   batch   = (const int*)d_in[3];
  const float* in_W    = (const float*)d_in[4];
  const float* in_b    = (const float*)d_in[5];
  const float* in_g    = (const float*)d_in[6];
  const float* in_beta = (const float*)d_in[7];
  const float* Wl      = (const float*)d_in[8];
  const float* Wr      = (const float*)d_in[9];
  const float* We      = (const float*)d_in[10];
  const float* att     = (const float*)d_in[11];
  const float* conv_b  = (const float*)d_in[12];
  const float* bn_g    = (const float*)d_in[13];
  const float* bn_b    = (const float*)d_in[14];
  const float* t1_W    = (const float*)d_in[15];
  const float* t1_b    = (const float*)d_in[16];
  const float* t1_g    = (const float*)d_in[17];
  const float* t1_beta = (const float*)d_in[18];
  const float* t2_W    = (const float*)d_in[19];
  const float* t2_b    = (const float*)d_in[20];
  const float* t2_g    = (const float*)d_in[21];
  const float* t2_beta = (const float*)d_in[22];
  const float* head_W  = (const float*)d_in[23];
  const float* head_b  = (const float*)d_in[24];
  float* out = (float*)d_out;

  float* p = (float*)d_ws;
  float* xn   = p; p += N_ * H_;
  float* buf  = p; p += N_ * H_;
  float* ssum = p; p += 256;
  float* ssq  = p; p += 256;   // contiguous after ssum (joint memset)
  float* mean = p; p += 256;
  float* rstd = p; p += 256;
  float* xg   = p; p += G_ * 384;
  float* u1   = p; p += G_ * 256;
  float* u2   = p; p += G_ * 128;
  unsigned* up = (unsigned*)p;
  unsigned* xlb  = up; up += (size_t)N_ * 64;
  unsigned* xrb  = up; up += (size_t)N_ * 64;
  unsigned* easb = up; up += (size_t)E_ * 4;
  int* ip = (int*)up;
  int* deg    = ip; ip += N_;
  int* eoff   = ip; ip += N_ + 1;
  int* cursor = ip; ip += N_;
  int* goff   = ip; ip += G_ + 1;
  int* esrc   = ip; ip += E_;
  int* bsum   = ip; ip += 64;
  int* boff   = ip; ip += 64;

  // ---- build CSR structures ----
  hipMemsetAsync(deg, 0, (size_t)N_ * sizeof(int), stream);
  hist_kernel<<<1024, 256, 0, stream>>>(ei + E_, E_, deg);
  scan_local<<<49, 1024, 0, stream>>>(deg, eoff, bsum, N_);
  scan_bsum<<<1, 64, 0, stream>>>(bsum, boff, 49);
  scan_add<<<49, 1024, 0, stream>>>(eoff, boff, cursor, N_);
  edge_scatter<<<(E_ + 255) / 256, 256, 0, stream>>>(ei, ea, cursor, esrc, easb);
  goff_from_sorted<<<(N_ + 255) / 256, 256, 0, stream>>>(batch, goff);

  // ---- input layer ----
  hipMemsetAsync(ssum, 0, 512 * sizeof(float), stream);
  in_gemm<<<(N_ + 31) / 32, 256, 0, stream>>>(x, in_W, in_b, buf, ssum, ssq);
  bn_final<<<1, 256, 0, stream>>>(ssum, ssq, 1.f / N_, H_, mean, rstd);

  // ---- 3 GATv2 layers ----
  for (int l = 0; l < 3; l++) {
    if (l == 0) {
      gemm_xlxr<1><<<(N_ + 63) / 64, 256, 0, stream>>>(xn, xn, buf, in_g, in_beta, mean, rstd,
                                                       Wl + l * H_ * H_, Wr + l * H_ * H_,
                                                       xlb, xrb);
    } else {
      gemm_xlxr<2><<<(N_ + 63) / 64, 256, 0, stream>>>(xn, xn, buf, bn_g + (l - 1) * H_,
                                                       bn_b + (l - 1) * H_, mean, rstd,
                                                       Wl + l * H_ * H_, Wr + l * H_ * H_,
                                                       xlb, xrb);
    }
    agg_csr<<<2048, 256, 0, stream>>>(eoff, esrc, easb, We + l * 8 * H_, att + l * H_,
                                      xlb, xrb, conv_b + l * H_, buf, ssum, ssq);
    bn_final<<<1, 256, 0, stream>>>(ssum, ssq, 1.f / N_, H_, mean, rstd);
  }

  // ---- pooling with fused layer-2 residual ----
  pool_residual<<<G_, 128, 0, stream>>>(goff, xn, buf, bn_g + 2 * H_, bn_b + 2 * H_,
                                        mean, rstd, xg);

  // ---- t1 ----
  mlp_gemm<384, 256><<<G_ / 8, 256, 0, stream>>>(xg, t1_W, t1_b, u1, G_, ssum, ssq);
  bn_final<<<1, 256, 0, stream>>>(ssum, ssq, 1.f / G_, 256, mean, rstd);
  apply_bn_relu<<<(G_ * 256 + 255) / 256, 256, 0, stream>>>(u1, u1, t1_g, t1_beta, mean, rstd,
                                                            (long)G_ * 256, 255);

  // ---- t2 ----
  mlp_gemm<256, 128><<<G_ / 8, 128, 0, stream>>>(u1, t2_W, t2_b, u2, G_, ssum, ssq);
  bn_final<<<1, 256, 0, stream>>>(ssum, ssq, 1.f / G_, 128, mean, rstd);
  apply_bn_relu<<<(G_ * 128 + 255) / 256, 256, 0, stream>>>(u2, u2, t2_g, t2_beta, mean, rstd,
                                                            (long)G_ * 128, 127);

  // ---- head ----
  head_kernel<<<G_, 64, 0, stream>>>(u2, head_W, head_b, out);
}